// Round 15
// baseline (1470.989 us; speedup 1.0000x reference)
//
#include <hip/hip_runtime.h>
#include <hip/hip_bf16.h>

#define TT 4096
#define SS 2048
#define BBATCH 2
#define DM 1024
#define NH 16
#define HD 64
#define FFD 4096
#define NL 4
#define VV 18691
#define VP 18816
#define APITCH 72
#define NXLM 147
#define SENT 0x3FFFFFFF

typedef __bf16 bf16x8 __attribute__((ext_vector_type(8)));
typedef float f32x4 __attribute__((ext_vector_type(4)));
typedef const __attribute__((address_space(1))) void* gas_t;
typedef __attribute__((address_space(3))) void* las_t;

__device__ __forceinline__ float bfb2f(unsigned short u) {
    union { unsigned int i; float f; } x;
    x.i = ((unsigned int)u) << 16;
    return x.f;
}
__device__ __forceinline__ unsigned short f2bfb(float f) {
    union { float f; unsigned int i; } x;
    x.f = f;
    unsigned int r = 0x7fffu + ((x.i >> 16) & 1u);
    x.i += r;
    return (unsigned short)(x.i >> 16);
}

__device__ __forceinline__ float wave_sum(float v) {
#pragma unroll
    for (int o = 32; o; o >>= 1) v += __shfl_xor(v, o, 64);
    return v;
}

__device__ __forceinline__ float block_sum256(float v) {
    __shared__ float sb[4];
    v = wave_sum(v);
    int wid = threadIdx.x >> 6;
    if ((threadIdx.x & 63) == 0) sb[wid] = v;
    __syncthreads();
    float t = sb[0] + sb[1] + sb[2] + sb[3];
    __syncthreads();
    return t;
}

// ---- weight fp32 -> bf16 conversion ----
__global__ __launch_bounds__(256) void cvtw_kernel(const float* __restrict__ src,
                                                   unsigned short* __restrict__ dst, int n)
{
    int i = (blockIdx.x * 256 + threadIdx.x) * 4;
    if (i >= n) return;
    float4 f = *reinterpret_cast<const float4*>(src + i);
    ushort4 u;
    u.x = f2bfb(f.x); u.y = f2bfb(f.y); u.z = f2bfb(f.z); u.w = f2bfb(f.w);
    *reinterpret_cast<ushort4*>(dst + i) = u;
}

__global__ __launch_bounds__(256) void cvtpad_kernel(const float* __restrict__ src,
                                                     unsigned short* __restrict__ dst,
                                                     int nreal, int ntot)
{
    int i = (blockIdx.x * 256 + threadIdx.x) * 4;
    if (i >= ntot) return;
    ushort4 u = {0, 0, 0, 0};
    if (i < nreal) {
        float4 f = *reinterpret_cast<const float4*>(src + i);
        u.x = f2bfb(f.x); u.y = f2bfb(f.y); u.z = f2bfb(f.z); u.w = f2bfb(f.w);
    }
    *reinterpret_cast<ushort4*>(dst + i) = u;
}

// rope cos/sin table: tab[s][j] = (cos, sin)(s * 10000^(-j/32))
__global__ __launch_bounds__(256) void ropetab_kernel(float2* __restrict__ tab)
{
    int s = blockIdx.x * 8 + (threadIdx.x >> 5);
    int j = threadIdx.x & 31;
    float invf = exp2f(-(float)j * 0.41524101186092025f);
    float ang = (float)s * invf;
    float sn, cs;
    sincosf(ang, &sn, &cs);
    tab[s * 32 + j] = make_float2(cs, sn);
}

// x = rms_norm(wte[idx]); x0 = bf16(x); levels[t]
__global__ __launch_bounds__(256) void embed_kernel(
    const int* __restrict__ idx, const float* __restrict__ wte,
    float* __restrict__ x, unsigned short* __restrict__ x0, int* __restrict__ levels)
{
    int t = blockIdx.x;
    int id = idx[t];
    const float* row = wte + (size_t)id * DM;
    float4 v = *reinterpret_cast<const float4*>(row + threadIdx.x * 4);
    float ss = v.x * v.x + v.y * v.y + v.z * v.z + v.w * v.w;
    float tot = block_sum256(ss);
    float rs = rsqrtf(tot / (float)DM + 1e-6f);
    float4 o;
    o.x = v.x * rs; o.y = v.y * rs; o.z = v.z * rs; o.w = v.w * rs;
    size_t off = (size_t)t * DM + threadIdx.x * 4;
    *reinterpret_cast<float4*>(x + off) = o;
    ushort4 ub;
    ub.x = f2bfb(o.x); ub.y = f2bfb(o.y); ub.z = f2bfb(o.z); ub.w = f2bfb(o.w);
    *reinterpret_cast<ushort4*>(x0 + off) = ub;
    if (threadIdx.x == 0) levels[t] = (id >= 16385) + (id >= 18434);
}

// per-batch ascending list of positions with level>0
__global__ __launch_bounds__(256) void pack_kernel(
    const int* __restrict__ levels, int* __restrict__ gpos, int* __restrict__ nbuf)
{
    int b = blockIdx.x;
    const int* lv = levels + b * SS;
    int* gp = gpos + b * SS;
    __shared__ int wsum[4];
    __shared__ int base;
    if (threadIdx.x == 0) base = 0;
    __syncthreads();
    int lane = threadIdx.x & 63, w = threadIdx.x >> 6;
    for (int c = 0; c < SS; c += 256) {
        int s = c + threadIdx.x;
        int flag = (lv[s] > 0) ? 1 : 0;
        unsigned long long mask = __ballot(flag);
        int pre = __popcll(mask & ((1ull << lane) - 1ull));
        int wtot = __popcll(mask);
        if (lane == 0) wsum[w] = wtot;
        __syncthreads();
        int woff = 0;
#pragma unroll
        for (int i = 0; i < 4; ++i) if (i < w) woff += wsum[i];
        int tot = wsum[0] + wsum[1] + wsum[2] + wsum[3];
        int mybase = base;
        if (flag) gp[mybase + woff + pre] = s;
        __syncthreads();
        if (threadIdx.x == 0) base += tot;
        __syncthreads();
    }
    int nb = base;
    int nbp = (nb + 63) & ~63;
    for (int i = nb + threadIdx.x; i < SS; i += 256) gp[i] = SENT;
    if (threadIdx.x == 0) { nbuf[b] = nb; nbuf[BBATCH + b] = nbp; }
}

// gather roped K and mixed V rows of level>0 positions into packed buffers
__global__ __launch_bounds__(64) void gather_kernel(
    const unsigned short* __restrict__ kb, const unsigned short* __restrict__ vb,
    const int* __restrict__ gpos, const int* __restrict__ nbuf,
    unsigned short* __restrict__ kp, unsigned short* __restrict__ vp)
{
    int b = blockIdx.x >> 11;
    int j = blockIdx.x & (SS - 1);
    if (j >= nbuf[BBATCH + b]) return;
    int pos = gpos[b * SS + j];
    int lane = threadIdx.x;
    size_t dst = ((size_t)b * SS + j) * DM + lane * 16;
    if (pos < SS) {
        size_t src = ((size_t)b * SS + pos) * DM + lane * 16;
        *reinterpret_cast<uint4*>(kp + dst) = *reinterpret_cast<const uint4*>(kb + src);
        *reinterpret_cast<uint4*>(kp + dst + 8) = *reinterpret_cast<const uint4*>(kb + src + 8);
        *reinterpret_cast<uint4*>(vp + dst) = *reinterpret_cast<const uint4*>(vb + src);
        *reinterpret_cast<uint4*>(vp + dst + 8) = *reinterpret_cast<const uint4*>(vb + src + 8);
    } else {
        uint4 z = {0, 0, 0, 0};
        *reinterpret_cast<uint4*>(kp + dst) = z;
        *reinterpret_cast<uint4*>(kp + dst + 8) = z;
        *reinterpret_cast<uint4*>(vp + dst) = z;
        *reinterpret_cast<uint4*>(vp + dst + 8) = z;
    }
}

// xr = l0*x + l1*x0 (written back to x); out = bf16(rms_norm(xr))
__global__ __launch_bounds__(256) void mixnorm_kernel(
    float* __restrict__ x, const unsigned short* __restrict__ x0,
    const float* __restrict__ lam2, unsigned short* __restrict__ out)
{
    int t = blockIdx.x;
    size_t off = (size_t)t * DM + threadIdx.x * 4;
    float4 xv = *reinterpret_cast<const float4*>(x + off);
    float l0 = lam2[0], l1 = lam2[1];
    ushort4 u = *reinterpret_cast<const ushort4*>(x0 + off);
    float4 r;
    r.x = l0 * xv.x + l1 * bfb2f(u.x);
    r.y = l0 * xv.y + l1 * bfb2f(u.y);
    r.z = l0 * xv.z + l1 * bfb2f(u.z);
    r.w = l0 * xv.w + l1 * bfb2f(u.w);
    float ss = r.x * r.x + r.y * r.y + r.z * r.z + r.w * r.w;
    float tot = block_sum256(ss);
    float rs = rsqrtf(tot / (float)DM + 1e-6f);
    *reinterpret_cast<float4*>(x + off) = r;
    ushort4 ob;
    ob.x = f2bfb(r.x * rs); ob.y = f2bfb(r.y * rs);
    ob.z = f2bfb(r.z * rs); ob.w = f2bfb(r.w * rs);
    *reinterpret_cast<ushort4*>(out + off) = ob;
}

// out = bf16(rms_norm(x)), x unmodified
__global__ __launch_bounds__(256) void norm_kernel(
    const float* __restrict__ x, unsigned short* __restrict__ out)
{
    int t = blockIdx.x;
    size_t off = (size_t)t * DM + threadIdx.x * 4;
    float4 r = *reinterpret_cast<const float4*>(x + off);
    float ss = r.x * r.x + r.y * r.y + r.z * r.z + r.w * r.w;
    float tot = block_sum256(ss);
    float rs = rsqrtf(tot / (float)DM + 1e-6f);
    ushort4 ob;
    ob.x = f2bfb(r.x * rs); ob.y = f2bfb(r.y * rs);
    ob.z = f2bfb(r.z * rs); ob.w = f2bfb(r.w * rs);
    *reinterpret_cast<ushort4*>(out + off) = ob;
}

// ---------- bf16-weight GEMM, m97 structure, 128x128 tile ----------
// DEC 0: row-major tile decode. DEC 1: 2-D XCD partition for nwg=1024/NX=32 (w1):
//   XCD (mi,nj) owns by in [8mi,8mi+8) x bx in [16nj,16nj+16); bx-outer/by-inner(8).
// EPI 0: C bf16. EPI 1: relu(acc)^2 bf16. EPI 2: Cf fp32 += acc.
// EPI 3: fused QKV split; q/k get fused head-rms_norm+rope; v gets v1 copy/mix.
template <int EPI, int DEC = 0>
__global__ __launch_bounds__(256) void gemm_bb(
    const unsigned short* __restrict__ A, const unsigned short* __restrict__ Bw,
    unsigned short* __restrict__ Cb, float* __restrict__ Cf,
    unsigned short* __restrict__ Kb, unsigned short* __restrict__ Vb,
    const unsigned short* __restrict__ V1in, unsigned short* __restrict__ V1out,
    const float* __restrict__ lambp, const float2* __restrict__ tab,
    int NX, int K, int ldC)
{
    __shared__ unsigned short As[128 * 64];
    __shared__ unsigned short Bs[128 * 64];

    int orig = blockIdx.x;
    int bx, by;
    if constexpr (DEC == 1) {
        int xcd = orig & 7, rank = orig >> 3;   // rank in 0..127
        int mi = xcd >> 1, nj = xcd & 1;
        bx = nj * 16 + (rank >> 3);
        by = mi * 8 + (rank & 7);
    } else {
        int nwg = gridDim.x;
        int qq = nwg >> 3, rr = nwg & 7;
        int xcd = orig & 7, rem = orig >> 3;
        int wg = (xcd < rr ? xcd * (qq + 1) : rr * (qq + 1) + (xcd - rr) * qq) + rem;
        bx = wg % NX; by = wg / NX;
    }
    int m0 = by * 128, n0 = bx * 128;

    int tid = threadIdx.x, lane = tid & 63, w = tid >> 6;
    int wr = w >> 1, wc = w & 1;
    int rsub = lane >> 3, sl = lane & 7;
    int ssrc = sl ^ rsub;           // inverse-swizzled source slot
    int fr = lane & 15, fh = lane >> 4;

    size_t arow[4], brow[4];
#pragma unroll
    for (int i = 0; i < 4; ++i) {
        int c = 4 * w + i;
        arow[i] = (size_t)(m0 + 8 * c + rsub) * K + ssrc * 8;
        brow[i] = (size_t)(n0 + 8 * c + rsub) * K + ssrc * 8;
    }

    f32x4 acc[4][4];
#pragma unroll
    for (int m = 0; m < 4; ++m)
#pragma unroll
        for (int n = 0; n < 4; ++n) acc[m][n] = 0.0f;

    int NT = K >> 6;
    for (int kt = 0; kt < NT; ++kt) {
        int kb = kt * 64;
#pragma unroll
        for (int i = 0; i < 4; ++i) {
            __builtin_amdgcn_global_load_lds((gas_t)(const void*)(A + arow[i] + kb),
                                             (las_t)(void*)(&As[(4 * w + i) * 512]), 16, 0, 0);
            __builtin_amdgcn_global_load_lds((gas_t)(const void*)(Bw + brow[i] + kb),
                                             (las_t)(void*)(&Bs[(4 * w + i) * 512]), 16, 0, 0);
        }
        __syncthreads();
#pragma unroll
        for (int kk = 0; kk < 2; ++kk) {
            int slot = kk * 4 + fh;
            bf16x8 af[4], bfv[4];
#pragma unroll
            for (int m = 0; m < 4; ++m) {
                int row = wr * 64 + m * 16 + fr;
                af[m] = *reinterpret_cast<const bf16x8*>(&As[row * 64 + ((slot ^ (row & 7)) << 3)]);
            }
#pragma unroll
            for (int n = 0; n < 4; ++n) {
                int row = wc * 64 + n * 16 + fr;
                bfv[n] = *reinterpret_cast<const bf16x8*>(&Bs[row * 64 + ((slot ^ (row & 7)) << 3)]);
            }
#pragma unroll
            for (int m = 0; m < 4; ++m)
#pragma unroll
                for (int n = 0; n < 4; ++n)
                    acc[m][n] = __builtin_amdgcn_mfma_f32_16x16x32_bf16(af[m], bfv[n], acc[m][n], 0, 0, 0);
        }
        __syncthreads();
    }

    int rb = m0 + wr * 64 + fh * 4;
    int cb = n0 + wc * 64 + fr;

    if constexpr (EPI == 3) {
        int mat = n0 >> 10;
        if (mat < 2) {
            // fused per-head rms_norm + rope for q (mat 0) / k (mat 1)
            unsigned short* outp = (mat == 0) ? Cb : Kb;
#pragma unroll
            for (int m = 0; m < 4; ++m) {
#pragma unroll
                for (int j = 0; j < 4; ++j) {
                    int gr = rb + m * 16 + j;
                    int s = gr & (SS - 1);
                    float ss = 0.0f;
#pragma unroll
                    for (int n = 0; n < 4; ++n) ss += acc[m][n][j] * acc[m][n][j];
                    ss += __shfl_xor(ss, 1, 64);
                    ss += __shfl_xor(ss, 2, 64);
                    ss += __shfl_xor(ss, 4, 64);
                    ss += __shfl_xor(ss, 8, 64);
                    float rsn = rsqrtf(ss * (1.0f / (float)HD) + 1e-6f);
                    float nv0 = acc[m][0][j] * rsn;
                    float nv1 = acc[m][1][j] * rsn;
                    float nv2 = acc[m][2][j] * rsn;
                    float nv3 = acc[m][3][j] * rsn;
                    float2 t0 = tab[s * 32 + fr];
                    float2 t1 = tab[s * 32 + fr + 16];
                    float o0 = nv0 * t0.x + nv2 * t0.y;
                    float o1 = nv1 * t1.x + nv3 * t1.y;
                    float o2 = nv2 * t0.x - nv0 * t0.y;
                    float o3 = nv3 * t1.x - nv1 * t1.y;
                    size_t rowo = (size_t)gr * DM + ((cb)&1023);
                    outp[rowo] = f2bfb(o0);
                    outp[rowo + 16] = f2bfb(o1);
                    outp[rowo + 32] = f2bfb(o2);
                    outp[rowo + 48] = f2bfb(o3);
                }
            }
        } else {
            // v path: copy (layer 0) or mix with v1
            float la = V1out ? 0.0f : *lambp;
#pragma unroll
            for (int n = 0; n < 4; ++n) {
                int gc = cb + n * 16;
#pragma unroll
                for (int m = 0; m < 4; ++m) {
#pragma unroll
                    for (int j = 0; j < 4; ++j) {
                        int gr = rb + m * 16 + j;
                        size_t o = (size_t)gr * DM + (gc & 1023);
                        unsigned short bv = f2bfb(acc[m][n][j]);
                        if (V1out) {
                            Vb[o] = bv;
                            V1out[o] = bv;
                        } else {
                            float mixed = (1.0f - la) * bfb2f(bv) + la * bfb2f(V1in[o]);
                            Vb[o] = f2bfb(mixed);
                        }
                    }
                }
            }
        }
        return;
    }

#pragma unroll
    for (int n = 0; n < 4; ++n) {
        int gc = cb + n * 16;
#pragma unroll
        for (int m = 0; m < 4; ++m) {
#pragma unroll
            for (int j = 0; j < 4; ++j) {
                int gr = rb + m * 16 + j;
                float val = acc[m][n][j];
                if constexpr (EPI == 0) {
                    Cb[(size_t)gr * ldC + gc] = f2bfb(val);
                } else if constexpr (EPI == 1) {
                    float rl = fmaxf(val, 0.0f);
                    Cb[(size_t)gr * ldC + gc] = f2bfb(rl * rl);
                } else if constexpr (EPI == 2) {
                    size_t o = (size_t)gr * ldC + gc;
                    Cf[o] = Cf[o] + val;
                }
            }
        }
    }
}

// ---------- lm_head GEMM (single-buffer), fused softcap+exp partial-sum ----------
// exp(softcap(z)-30) == exp(-60/(t+1)) with t = exp(z/15)   [exact identity]
__global__ __launch_bounds__(256) void gemm_lm(
    const unsigned short* __restrict__ A, const unsigned short* __restrict__ Bw,
    const int* __restrict__ target, float* __restrict__ part, float* __restrict__ zbf,
    int K)
{
    __shared__ unsigned short As[128 * 64];
    __shared__ unsigned short Bs[128 * 64];
    __shared__ float reds[2][2][64];

    // bijective xcd chunking: nwg = 4704 = 8 * 588
    int orig = blockIdx.x;
    int xcd = orig & 7, rank = orig >> 3;
    int e = xcd * 588 + rank;
    int g = 0;
#pragma unroll
    for (int it = 0; it < 7; ++it) {
        int sz = (g & 1) ? 584 : 592;
        if (e >= sz) { e -= sz; ++g; }
    }
    int nj = g & 1, mi = g >> 1;
    int bxl = e >> 3, byl = e & 7;
    int bx = nj * 74 + bxl;
    int by = mi * 8 + byl;
    int m0 = by * 128, n0 = bx * 128;

    int tid = threadIdx.x, lane = tid & 63, w = tid >> 6;
    int wr = w >> 1, wc = w & 1;
    int rsub = lane >> 3, sl = lane & 7;
    int ssrc = sl ^ rsub;
    int fr = lane & 15, fh = lane >> 4;

    size_t arow[4], brow[4];
#pragma unroll
    for (int i = 0; i < 4; ++i) {
        int c = 4 * w + i;
        arow[i] = (size_t)(m0 + 8 * c + rsub) * K + ssrc * 8;
        brow[i] = (size_t)(n0 + 8 * c + rsub) * K + ssrc * 8;
    }

    f32x4 acc[4][4];
#pragma unroll
    for (int m = 0; m < 4; ++m)
#pragma unroll
        for (int n = 0; n < 4; ++n) acc[m][n] = 0.0f;

    int NT = K >> 6;
    for (int kt = 0; kt < NT; ++kt) {
        int kb = kt * 64;
#pragma unroll
        for (int i = 0; i < 4; ++i) {
            __builtin_amdgcn_global_load_lds((gas_t)(const void*)(A + arow[i] + kb),
                                             (las_t)(void*)(&As[(4 * w + i) * 512]), 16, 0, 0);
            __builtin_amdgcn_global_load_lds((gas_t)(const void*)(Bw + brow[i] + kb),
                                             (las_t)(void*)(&Bs[(4 * w + i) * 512]), 16, 0, 0);
        }
        __syncthreads();
#pragma unroll
        for (int kk = 0; kk < 2; ++kk) {
            int slot = kk * 4 + fh;
            bf16x8 af[4], bfv[4];
#pragma unroll
            for (int m = 0; m < 4; ++m) {
                int row = wr * 64 + m * 16 + fr;
                af[m] = *reinterpret_cast<const bf16x8*>(&As[row * 64 + ((slot ^ (row & 7)) << 3)]);
            }
#pragma unroll
            for (int n = 0; n < 4; ++n) {
                int row = wc * 64 + n * 16 + fr;
                bfv[n] = *reinterpret_cast<const bf16x8*>(&Bs[row * 64 + ((slot ^ (row & 7)) << 3)]);
            }
#pragma unroll
            for (int m = 0; m < 4; ++m)
#pragma unroll
                for (int n = 0; n < 4; ++n)
                    acc[m][n] = __builtin_amdgcn_mfma_f32_16x16x32_bf16(af[m], bfv[n], acc[m][n], 0, 0, 0);
        }
        __syncthreads();
    }

    int rb = m0 + wr * 64 + fh * 4;
    int cb = n0 + wc * 64 + fr;
#pragma unroll
    for (int m = 0; m < 4; ++m) {
#pragma unroll
        for (int j = 0; j < 4; ++j) {
            int gr = rb + m * 16 + j;
            int tg = target[gr];
            float rs = 0.0f;
#pragma unroll
            for (int n = 0; n < 4; ++n) {
                int gc = cb + n * 16;
                if (gc < VV) {
                    float zv = acc[m][n][j];
                    float tt = __expf(zv * 0.066666667f);     // exp(z/15)
                    rs += __expf(__fdividef(-60.0f, tt + 1.0f));
                    if (gc == tg) zbf[gr] = 30.0f - 60.0f / (tt + 1.0f);
                }
            }
            rs += __shfl_xor(rs, 1, 64);
            rs += __shfl_xor(rs, 2, 64);
            rs += __shfl_xor(rs, 4, 64);
            rs += __shfl_xor(rs, 8, 64);
            if (fr == 0) reds[wr][wc][m * 16 + fh * 4 + j] = rs;
        }
    }
    __syncthreads();
    if (tid < 128) {
        int wrx = tid >> 6, r64 = tid & 63;
        part[(size_t)(m0 + tid) * NXLM + bx] = reds[wrx][0][r64] + reds[wrx][1][r64];
    }
}

// merge NXLM partial sums per token -> loss = 30 + log(sum) - z_target
__global__ __launch_bounds__(256) void loss_merge_kernel(
    const float* __restrict__ part, const float* __restrict__ zbf,
    const int* __restrict__ target, float* __restrict__ out)
{
    int t = blockIdx.x;
    float l = 0.0f;
    for (int i = threadIdx.x; i < NXLM; i += 256) l += part[(size_t)t * NXLM + i];
    l = block_sum256(l);
    if (threadIdx.x == 0) {
        int tg = target[t];
        float lse = 30.0f + logf(l);
        bool masked = (tg == 16384) || (tg == 18433) || (tg == 18690);
        out[t] = masked ? 0.0f : (lse - zbf[t]);
    }
}

// ---------- BM=64 variant for small-N GEMMs (wo, w2) ----------
template <int EPI>
__global__ __launch_bounds__(256) void gemm_bb64(
    const unsigned short* __restrict__ A, const unsigned short* __restrict__ Bw,
    unsigned short* __restrict__ Cb, float* __restrict__ Cf,
    int NX, int K, int ldC)
{
    __shared__ unsigned short As[64 * 64];
    __shared__ unsigned short Bs[128 * 64];

    int nwg = gridDim.x;
    int orig = blockIdx.x;
    int qq = nwg >> 3, rr = nwg & 7;
    int xcd = orig & 7, rem = orig >> 3;
    int wg = (xcd < rr ? xcd * (qq + 1) : rr * (qq + 1) + (xcd - rr) * qq) + rem;
    int bx = wg % NX, by = wg / NX;
    int m0 = by * 64, n0 = bx * 128;

    int tid = threadIdx.x, lane = tid & 63, w = tid >> 6;
    int wr = w >> 1, wc = w & 1;
    int rsub = lane >> 3, sl = lane & 7;
    int ssrc = sl ^ rsub;
    int fr = lane & 15, fh = lane >> 4;

    size_t arow[2], brow[4];
#pragma unroll
    for (int i = 0; i < 2; ++i) {
        int c = 2 * w + i;
        arow[i] = (size_t)(m0 + 8 * c + rsub) * K + ssrc * 8;
    }
#pragma unroll
    for (int i = 0; i < 4; ++i) {
        int c = 4 * w + i;
        brow[i] = (size_t)(n0 + 8 * c + rsub) * K + ssrc * 8;
    }

    f32x4 acc[2][4];
#pragma unroll
    for (int m = 0; m < 2; ++m)
#pragma unroll
        for (int n = 0; n < 4; ++n) acc[m][n] = 0.0f;

    int NT = K >> 6;
    for (int kt = 0; kt < NT; ++kt) {
        int kb = kt * 64;
#pragma unroll
        for (int i = 0; i < 2; ++i)
            __builtin_amdgcn_global_load_lds((gas_t)(const void*)(A + arow[i] + kb),
                                             (las_t)(void*)(&As[(2 * w + i) * 512]), 16, 0, 0);
#pragma unroll
        for (int i = 0; i < 4; ++i)
            __builtin_amdgcn_global_load_lds((gas_t)(const void*)(Bw + brow[i] + kb),
                                             (las_t)(void*)(&Bs[(4 * w + i) * 512]), 16, 0, 0);
        __syncthreads();
#pragma unroll
        for (int kk = 0; kk < 2; ++kk) {
            int slot = kk * 4 + fh;
            bf16x8 af[2], bfv[4];
#pragma unroll
            for (int m = 0; m < 2; ++m) {
                int row = wr * 32 + m * 16 + fr;
                af[m] = *reinterpret_cast<const bf16x8*>(&As[row * 64 + ((slot ^ (row & 7)) << 3)]);
            }
#pragma unroll
            for (int n = 0; n < 4; ++n) {
                int row = wc * 64 + n * 16 + fr;
                bfv[n] = *reinterpret_cast<const bf16x8*>(&Bs[row * 64 + ((slot ^ (row & 7)) << 3)]);
            }
#pragma unroll
            for (int m = 0; m < 2; ++m)
#pragma unroll
                for (int n = 0; n < 4; ++n)
                    acc[m][n] = __builtin_amdgcn_mfma_f32_16x16x32_bf16(af[m], bfv[n], acc[m][n], 0, 0, 0);
        }
        __syncthreads();
    }

    int rb = m0 + wr * 32 + fh * 4;
    int cb = n0 + wc * 64 + fr;
#pragma unroll
    for (int n = 0; n < 4; ++n) {
        int gc = cb + n * 16;
#pragma unroll
        for (int m = 0; m < 2; ++m) {
#pragma unroll
            for (int j = 0; j < 4; ++j) {
                int gr = rb + m * 16 + j;
                float val = acc[m][n][j];
                if constexpr (EPI == 0) {
                    Cb[(size_t)gr * ldC + gc] = f2bfb(val);
                } else if constexpr (EPI == 1) {
                    float rl = fmaxf(val, 0.0f);
                    Cb[(size_t)gr * ldC + gc] = f2bfb(rl * rl);
                } else {
                    size_t o = (size_t)gr * ldC + gc;
                    Cf[o] = Cf[o] + val;
                }
            }
        }
    }
}

// MFMA flash attention, mask-sparse: local sliding-window pass + packed level>0 pass.
__global__ __launch_bounds__(256) void attn_mfma_kernel(
    const unsigned short* __restrict__ q, const unsigned short* __restrict__ k,
    const unsigned short* __restrict__ v,
    const unsigned short* __restrict__ kp, const unsigned short* __restrict__ vp,
    const int* __restrict__ gpos, const int* __restrict__ nbuf,
    unsigned short* __restrict__ y)
{
    __shared__ unsigned short Qs[64][APITCH];
    __shared__ unsigned short Ks[64][APITCH];
    __shared__ unsigned short Vt[64][APITCH];
    __shared__ unsigned short Ps[64][APITCH];
    __shared__ int posS[64];

    int bh = blockIdx.x;
    int b = bh >> 4, h = bh & 15;
    int q0 = blockIdx.y * 64;
    size_t base = (size_t)b * SS * DM + h * HD;
    int tid = threadIdx.x;
    int lane = tid & 63, w = tid >> 6;
    int srow = tid >> 2, sc = tid & 3;

    {
        const unsigned short* src = q + base + (size_t)(q0 + srow) * DM;
        *reinterpret_cast<uint4*>(&Qs[srow][sc * 8]) = *reinterpret_cast<const uint4*>(src + sc * 8);
        *reinterpret_cast<uint4*>(&Qs[srow][(sc + 4) * 8]) = *reinterpret_cast<const uint4*>(src + (sc + 4) * 8);
    }
    __syncthreads();

    int fr = lane & 15, fc = (lane >> 4) * 8;
    int rj = (lane >> 4) * 4;

    bf16x8 qa[2];
    qa[0] = *reinterpret_cast<const bf16x8*>(&Qs[w * 16 + fr][fc]);
    qa[1] = *reinterpret_cast<const bf16x8*>(&Qs[w * 16 + fr][32 + fc]);

    float mreg[4], lreg[4];
    f32x4 yacc[4];
#pragma unroll
    for (int j = 0; j < 4; ++j) { mreg[j] = -1e30f; lreg[j] = 0.0f; yacc[j] = 0.0f; }

    int nbp = nbuf[BBATCH + b];

    int t0 = (q0 >= 256) ? ((q0 - 256) >> 6) : 0;
    int t1 = q0 >> 6;
    for (int pass = 0; pass < 2; ++pass) {
        int kt_begin = (pass == 0) ? t0 : 0;
        int kt_end = (pass == 0) ? (t1 + 1) : (nbp >> 6);
        for (int kt = kt_begin; kt < kt_end; ++kt) {
            int k0 = kt * 64;
            if (pass == 1) {
                if (gpos[b * SS + k0] > q0 - 194) break;
            }
            __syncthreads();
            {
                const unsigned short* ksrc = (pass == 0) ? (k + base) : (kp + base);
                const unsigned short* vsrc = (pass == 0) ? (v + base) : (vp + base);
                size_t goff = (size_t)(k0 + srow) * DM;
                uint4 kv0 = *reinterpret_cast<const uint4*>(ksrc + goff + sc * 8);
                uint4 kv1 = *reinterpret_cast<const uint4*>(ksrc + goff + (sc + 4) * 8);
                *reinterpret_cast<uint4*>(&Ks[srow][sc * 8]) = kv0;
                *reinterpret_cast<uint4*>(&Ks[srow][(sc + 4) * 8]) = kv1;
                uint4 vv0 = *reinterpret_cast<const uint4*>(vsrc + goff + sc * 8);
                uint4 vv1 = *reinterpret_cast<const uint4*>(vsrc + goff + (sc + 4) * 8);
                const unsigned short* e0 = reinterpret_cast<const unsigned short*>(&vv0);
                const unsigned short* e1 = reinterpret_cast<const unsigned short*>(&vv1);
#pragma unroll
                for (int i = 0; i < 8; ++i) Vt[sc * 8 + i][srow] = e0[i];
#pragma unroll
                for (int i = 0; i < 8; ++i) Vt[(sc + 4) * 8 + i][srow] = e1[i];
                if (pass == 1 && tid < 64) posS[tid] = gpos[b * SS + k0 + tid];
            }
            __syncthreads();

            f32x4 sacc[4];
#pragma unroll
            for (int n = 0; n < 4; ++n) {
                bf16x8 kb0 = *reinterpret_cast<const bf16x8*>(&Ks[n * 16 + fr][fc]);
                bf16x8 kb1 = *reinterpret_cast<const bf16x8*>(&Ks[n * 16 + fr][32 + fc]);
                f32x4 a = {0.0f, 0.0f, 0.0f, 0.0f};
                a = __builtin_amdgcn_mfma_f32_16x16x32_bf16(qa[0], kb0, a, 0, 0, 0);
                a = __builtin_amdgcn_mfma_f32_16x16x32_bf16(qa[1], kb1, a, 0, 0, 0);
                sacc[n] = a;
            }

            float sm[4][4];
            float cm[4] = {-1e30f, -1e30f, -1e30f, -1e30f};
#pragma unroll
            for (int n = 0; n < 4; ++n) {
                int kg = (pass == 0) ? (k0 + n * 16 + fr) : posS[n * 16 + fr];
#pragma unroll
                for (int j = 0; j < 4; ++j) {
                    int qg = q0 + w * 16 + rj + j;
                    bool valid = (pass == 0) ? ((kg <= qg) && (qg - kg <= 256))
                                             : (kg < qg - 256);
                    float s = valid ? sacc[n][j] * 0.125f : -1e30f;
                    sm[n][j] = s;
                    cm[j] = fmaxf(cm[j], s);
                }
            }
#pragma unroll
            for (int j = 0; j < 4; ++j) {
                cm[j] = fmaxf(cm[j], __shfl_xor(cm[j], 1, 64));
                cm[j] = fmaxf(cm[j], __shfl_xor(cm[j], 2, 64));
                cm[j] = fmaxf(cm[j], __shfl_xor(cm[j], 4, 64));
                cm[j] = fmaxf(cm[j], __shfl_xor(cm[j], 8, 64));
            }
            float sj[4], ps[4];
#pragma unroll
            for (int j = 0; j < 4; ++j) {
                float nm = fmaxf(mreg[j], cm[j]);
                sj[j] = __expf(mreg[j] - nm);
                mreg[j] = nm;
                ps[j] = 0.0f;
            }
#pragma unroll
            for (int n = 0; n < 4; ++n) {
#pragma unroll
                for (int j = 0; j < 4; ++j) {
                    float p = (sm[n][j] > -1e29f) ? __expf(sm[n][j] - mreg[j]) : 0.0f;
                    Ps[w * 16 + rj + j][n * 16 + fr] = f2bfb(p);
                    ps[j] += p;
                }
            }
#pragma unroll
            for (int j = 0; j < 4; ++j) {
                float t = ps[j];
                t += __shfl_xor(t, 1, 64); t += __shfl_xor(t, 2, 64);
                t += __shfl_xor(t, 4, 64); t += __shfl_xor(t, 8, 64);
                lreg[j] = lreg[j] * sj[j] + t;
            }
#pragma unroll
            for (int n = 0; n < 4; ++n)
#pragma unroll
                for (int j = 0; j < 4; ++j) yacc[n][j] *= sj[j];

            bf16x8 pa0 = *reinterpret_cast<const bf16x8*>(&Ps[w * 16 + fr][fc]);
            bf16x8 pa1 = *reinterpret_cast<const bf16x8*>(&Ps[w * 16 + fr][32 + fc]);
#pragma unroll
            for (int n = 0; n < 4; ++n) {
                bf16x8 vb0 = *reinterpret_cast<const bf16x8*>(&Vt[n * 16 + fr][fc]);
                bf16x8 vb1 = *reinterpret_cast<const bf16x8*>(&Vt[n * 16 + fr][32 + fc]);
                yacc[n] = __builtin_amdgcn_mfma_f32_16x16x32_bf16(pa0, vb0, yacc[n], 0, 0, 0);
                yacc[n] = __builtin_amdgcn_mfma_f32_16x16x32_bf16(pa1, vb1, yacc[n], 0, 0, 0);
            }
        }
    }

    float inv[4];
#pragma unroll
    for (int j = 0; j < 4; ++j) inv[j] = 1.0f / lreg[j];
#pragma unroll
    for (int n = 0; n < 4; ++n) {
#pragma unroll
        for (int j = 0; j < 4; ++j) {
            int qg = q0 + w * 16 + rj + j;
            y[base + (size_t)qg * DM + n * 16 + fr] = f2bfb(yacc[n][j] * inv[j]);
        }
    }
}

extern "C" void kernel_launch(void* const* d_in, const int* in_sizes, int n_in,
                              void* d_out, int out_size, void* d_ws, size_t ws_size,
                              hipStream_t stream)
{
    const int* idx = (const int*)d_in[0];
    const int* target = (const int*)d_in[1];
    const float* wte = (const float*)d_in[2];
    const float* lambdas = (const float*)d_in[3];
    const float* lamb = (const float*)d_in[4];
    const float* wq = (const float*)d_in[5];
    const float* wk = (const float*)d_in[6];
    const float* wv = (const float*)d_in[7];
    const float* wo = (const float*)d_in[8];
    const float* w1 = (const float*)d_in[9];
    const float* w2 = (const float*)d_in[10];
    const float* lm_head = (const float*)d_in[11];
    float* out = (float*)d_out;

    char* ws = (char*)d_ws;
    const size_t MB = (size_t)1 << 20;
    float* x            = (float*)(ws);
    unsigned short* x0  = (unsigned short*)(ws + 16 * MB);
    unsigned short* nrm = (unsigned short*)(ws + 24 * MB);
    unsigned short* qb  = (unsigned short*)(ws + 32 * MB);
    unsigned short* kb  = (unsigned short*)(ws + 40 * MB);
    unsigned short* vb  = (unsigned short*)(ws + 48 * MB);
    unsigned short* v1b = (unsigned short*)(ws + 56 * MB);
    unsigned short* yb  = (unsigned short*)(ws + 64 * MB);
    unsigned short* hid = (unsigned short*)(ws + 72 * MB);   // 32 MB; dead during attention & lm
    unsigned short* kp  = (unsigned short*)(ws + 72 * MB);   // packed K (8 MB), overlaps hid
    unsigned short* vp  = (unsigned short*)(ws + 80 * MB);   // packed V (8 MB), overlaps hid
    float* part         = (float*)(ws + 72 * MB);            // lm partials (2.4 MB), lm-time only
    float* zbf          = (float*)(ws + 78 * MB);            // lm target logit (16 KB), lm-time only
    int* levels         = (int*)(ws + 104 * MB);
    int* gpos           = (int*)(ws + 104 * MB + 64 * 1024);
    int* nbuf           = (int*)(ws + 104 * MB + 128 * 1024);
    float2* ropetab     = (float2*)(ws + 104 * MB + 256 * 1024); // 512 KB, persistent
    unsigned short* wqkvb = (unsigned short*)(ws + 105 * MB); // [NL][3][1024][1024]
    unsigned short* wob = (unsigned short*)(ws + 129 * MB);
    unsigned short* w1b = (unsigned short*)(ws + 137 * MB);
    unsigned short* w2b = (unsigned short*)(ws + 169 * MB);
    unsigned short* lmb = (unsigned short*)(ws + 201 * MB);
    bool cvt = ws_size >= 238 * MB;

    if (cvt) {
        int n1 = DM * DM;
        int nff = NL * FFD * DM;
        for (int i = 0; i < NL; ++i) {
            cvtw_kernel<<<n1 / 1024, 256, 0, stream>>>(wq + (size_t)i * n1, wqkvb + ((size_t)i * 3 + 0) * n1, n1);
            cvtw_kernel<<<n1 / 1024, 256, 0, stream>>>(wk + (size_t)i * n1, wqkvb + ((size_t)i * 3 + 1) * n1, n1);
            cvtw_kernel<<<n1 / 1024, 256, 0, stream>>>(wv + (size_t)i * n1, wqkvb + ((size_t)i * 3 + 2) * n1, n1);
        }
        cvtw_kernel<<<NL * n1 / 1024, 256, 0, stream>>>(wo, wob, NL * n1);
        cvtw_kernel<<<nff / 1024, 256, 0, stream>>>(w1, w1b, nff);
        cvtw_kernel<<<nff / 1024, 256, 0, stream>>>(w2, w2b, nff);
        cvtpad_kernel<<<(VP * DM) / 1024, 256, 0, stream>>>(lm_head, lmb, VV * DM, VP * DM);
    }
    ropetab_kernel<<<SS / 8, 256, 0, stream>>>(ropetab);

    embed_kernel<<<TT, 256, 0, stream>>>(idx, wte, x, x0, levels);
    pack_kernel<<<BBATCH, 256, 0, stream>>>(levels, gpos, nbuf);

    for (int i = 0; i < NL; ++i) {
        mixnorm_kernel<<<TT, 256, 0, stream>>>(x, x0, lambdas + 2 * i, nrm);
        if (cvt) {
            if (i == 0)
                gemm_bb<3><<<768, 256, 0, stream>>>(nrm, wqkvb + (size_t)i * 3 * DM * DM,
                                                    qb, nullptr, kb, vb, nullptr, v1b, nullptr, ropetab, 24, DM, DM);
            else
                gemm_bb<3><<<768, 256, 0, stream>>>(nrm, wqkvb + (size_t)i * 3 * DM * DM,
                                                    qb, nullptr, kb, vb, v1b, nullptr, lamb + i, ropetab, 24, DM, DM);
        }
        gather_kernel<<<BBATCH * SS, 64, 0, stream>>>(kb, vb, gpos, nbuf, kp, vp);
        attn_mfma_kernel<<<dim3(BBATCH * NH, SS / 64), 256, 0, stream>>>(qb, kb, vb, kp, vp, gpos, nbuf, yb);
        if (cvt) {
            gemm_bb64<2><<<512, 256, 0, stream>>>(yb, wob + (size_t)i * DM * DM, nullptr, x, 8, DM, DM);
            norm_kernel<<<TT, 256, 0, stream>>>(x, nrm);
            gemm_bb<1, 1><<<1024, 256, 0, stream>>>(nrm, w1b + (size_t)i * FFD * DM, hid, nullptr,
                                                    nullptr, nullptr, nullptr, nullptr, nullptr, nullptr, 32, DM, FFD);
            gemm_bb64<2><<<512, 256, 0, stream>>>(hid, w2b + (size_t)i * DM * FFD, nullptr, x, 8, FFD, DM);
        }
    }

    norm_kernel<<<TT, 256, 0, stream>>>(x, nrm);
    gemm_lm<<<NXLM * 32, 256, 0, stream>>>(nrm, lmb, target, part, zbf, DM);
    loss_merge_kernel<<<TT, 256, 0, stream>>>(part, zbf, target, out);
}

// Round 16
// 1430.659 us; speedup vs baseline: 1.0282x; 1.0282x over previous
//
#include <hip/hip_runtime.h>
#include <hip/hip_bf16.h>

#define TT 4096
#define SS 2048
#define BBATCH 2
#define DM 1024
#define NH 16
#define HD 64
#define FFD 4096
#define NL 4
#define VV 18691
#define VP 18816
#define APITCH 72
#define NXLM 147
#define SENT 0x3FFFFFFF

typedef __bf16 bf16x8 __attribute__((ext_vector_type(8)));
typedef float f32x4 __attribute__((ext_vector_type(4)));
typedef const __attribute__((address_space(1))) void* gas_t;
typedef __attribute__((address_space(3))) void* las_t;

__device__ __forceinline__ float bfb2f(unsigned short u) {
    union { unsigned int i; float f; } x;
    x.i = ((unsigned int)u) << 16;
    return x.f;
}
__device__ __forceinline__ unsigned short f2bfb(float f) {
    union { float f; unsigned int i; } x;
    x.f = f;
    unsigned int r = 0x7fffu + ((x.i >> 16) & 1u);
    x.i += r;
    return (unsigned short)(x.i >> 16);
}

__device__ __forceinline__ float wave_sum(float v) {
#pragma unroll
    for (int o = 32; o; o >>= 1) v += __shfl_xor(v, o, 64);
    return v;
}

__device__ __forceinline__ float block_sum256(float v) {
    __shared__ float sb[4];
    v = wave_sum(v);
    int wid = threadIdx.x >> 6;
    if ((threadIdx.x & 63) == 0) sb[wid] = v;
    __syncthreads();
    float t = sb[0] + sb[1] + sb[2] + sb[3];
    __syncthreads();
    return t;
}

// ---- weight fp32 -> bf16 conversion ----
__global__ __launch_bounds__(256) void cvtw_kernel(const float* __restrict__ src,
                                                   unsigned short* __restrict__ dst, int n)
{
    int i = (blockIdx.x * 256 + threadIdx.x) * 4;
    if (i >= n) return;
    float4 f = *reinterpret_cast<const float4*>(src + i);
    ushort4 u;
    u.x = f2bfb(f.x); u.y = f2bfb(f.y); u.z = f2bfb(f.z); u.w = f2bfb(f.w);
    *reinterpret_cast<ushort4*>(dst + i) = u;
}

__global__ __launch_bounds__(256) void cvtpad_kernel(const float* __restrict__ src,
                                                     unsigned short* __restrict__ dst,
                                                     int nreal, int ntot)
{
    int i = (blockIdx.x * 256 + threadIdx.x) * 4;
    if (i >= ntot) return;
    ushort4 u = {0, 0, 0, 0};
    if (i < nreal) {
        float4 f = *reinterpret_cast<const float4*>(src + i);
        u.x = f2bfb(f.x); u.y = f2bfb(f.y); u.z = f2bfb(f.z); u.w = f2bfb(f.w);
    }
    *reinterpret_cast<ushort4*>(dst + i) = u;
}

// rope cos/sin table: tab[s][j] = (cos, sin)(s * 10000^(-j/32))
__global__ __launch_bounds__(256) void ropetab_kernel(float2* __restrict__ tab)
{
    int s = blockIdx.x * 8 + (threadIdx.x >> 5);
    int j = threadIdx.x & 31;
    float invf = exp2f(-(float)j * 0.41524101186092025f);
    float ang = (float)s * invf;
    float sn, cs;
    sincosf(ang, &sn, &cs);
    tab[s * 32 + j] = make_float2(cs, sn);
}

// x = rms_norm(wte[idx]); x0 = bf16(x); levels[t]
__global__ __launch_bounds__(256) void embed_kernel(
    const int* __restrict__ idx, const float* __restrict__ wte,
    float* __restrict__ x, unsigned short* __restrict__ x0, int* __restrict__ levels)
{
    int t = blockIdx.x;
    int id = idx[t];
    const float* row = wte + (size_t)id * DM;
    float4 v = *reinterpret_cast<const float4*>(row + threadIdx.x * 4);
    float ss = v.x * v.x + v.y * v.y + v.z * v.z + v.w * v.w;
    float tot = block_sum256(ss);
    float rs = rsqrtf(tot / (float)DM + 1e-6f);
    float4 o;
    o.x = v.x * rs; o.y = v.y * rs; o.z = v.z * rs; o.w = v.w * rs;
    size_t off = (size_t)t * DM + threadIdx.x * 4;
    *reinterpret_cast<float4*>(x + off) = o;
    ushort4 ub;
    ub.x = f2bfb(o.x); ub.y = f2bfb(o.y); ub.z = f2bfb(o.z); ub.w = f2bfb(o.w);
    *reinterpret_cast<ushort4*>(x0 + off) = ub;
    if (threadIdx.x == 0) levels[t] = (id >= 16385) + (id >= 18434);
}

// per-batch ascending list of positions with level>0
__global__ __launch_bounds__(256) void pack_kernel(
    const int* __restrict__ levels, int* __restrict__ gpos, int* __restrict__ nbuf)
{
    int b = blockIdx.x;
    const int* lv = levels + b * SS;
    int* gp = gpos + b * SS;
    __shared__ int wsum[4];
    __shared__ int base;
    if (threadIdx.x == 0) base = 0;
    __syncthreads();
    int lane = threadIdx.x & 63, w = threadIdx.x >> 6;
    for (int c = 0; c < SS; c += 256) {
        int s = c + threadIdx.x;
        int flag = (lv[s] > 0) ? 1 : 0;
        unsigned long long mask = __ballot(flag);
        int pre = __popcll(mask & ((1ull << lane) - 1ull));
        int wtot = __popcll(mask);
        if (lane == 0) wsum[w] = wtot;
        __syncthreads();
        int woff = 0;
#pragma unroll
        for (int i = 0; i < 4; ++i) if (i < w) woff += wsum[i];
        int tot = wsum[0] + wsum[1] + wsum[2] + wsum[3];
        int mybase = base;
        if (flag) gp[mybase + woff + pre] = s;
        __syncthreads();
        if (threadIdx.x == 0) base += tot;
        __syncthreads();
    }
    int nb = base;
    int nbp = (nb + 63) & ~63;
    for (int i = nb + threadIdx.x; i < SS; i += 256) gp[i] = SENT;
    if (threadIdx.x == 0) { nbuf[b] = nb; nbuf[BBATCH + b] = nbp; }
}

// gather roped K and mixed V rows of level>0 positions into packed buffers
__global__ __launch_bounds__(64) void gather_kernel(
    const unsigned short* __restrict__ kb, const unsigned short* __restrict__ vb,
    const int* __restrict__ gpos, const int* __restrict__ nbuf,
    unsigned short* __restrict__ kp, unsigned short* __restrict__ vp)
{
    int b = blockIdx.x >> 11;
    int j = blockIdx.x & (SS - 1);
    if (j >= nbuf[BBATCH + b]) return;
    int pos = gpos[b * SS + j];
    int lane = threadIdx.x;
    size_t dst = ((size_t)b * SS + j) * DM + lane * 16;
    if (pos < SS) {
        size_t src = ((size_t)b * SS + pos) * DM + lane * 16;
        *reinterpret_cast<uint4*>(kp + dst) = *reinterpret_cast<const uint4*>(kb + src);
        *reinterpret_cast<uint4*>(kp + dst + 8) = *reinterpret_cast<const uint4*>(kb + src + 8);
        *reinterpret_cast<uint4*>(vp + dst) = *reinterpret_cast<const uint4*>(vb + src);
        *reinterpret_cast<uint4*>(vp + dst + 8) = *reinterpret_cast<const uint4*>(vb + src + 8);
    } else {
        uint4 z = {0, 0, 0, 0};
        *reinterpret_cast<uint4*>(kp + dst) = z;
        *reinterpret_cast<uint4*>(kp + dst + 8) = z;
        *reinterpret_cast<uint4*>(vp + dst) = z;
        *reinterpret_cast<uint4*>(vp + dst + 8) = z;
    }
}

// xr = l0*x + l1*x0 (written back to x); out = bf16(rms_norm(xr))
__global__ __launch_bounds__(256) void mixnorm_kernel(
    float* __restrict__ x, const unsigned short* __restrict__ x0,
    const float* __restrict__ lam2, unsigned short* __restrict__ out)
{
    int t = blockIdx.x;
    size_t off = (size_t)t * DM + threadIdx.x * 4;
    float4 xv = *reinterpret_cast<const float4*>(x + off);
    float l0 = lam2[0], l1 = lam2[1];
    ushort4 u = *reinterpret_cast<const ushort4*>(x0 + off);
    float4 r;
    r.x = l0 * xv.x + l1 * bfb2f(u.x);
    r.y = l0 * xv.y + l1 * bfb2f(u.y);
    r.z = l0 * xv.z + l1 * bfb2f(u.z);
    r.w = l0 * xv.w + l1 * bfb2f(u.w);
    float ss = r.x * r.x + r.y * r.y + r.z * r.z + r.w * r.w;
    float tot = block_sum256(ss);
    float rs = rsqrtf(tot / (float)DM + 1e-6f);
    *reinterpret_cast<float4*>(x + off) = r;
    ushort4 ob;
    ob.x = f2bfb(r.x * rs); ob.y = f2bfb(r.y * rs);
    ob.z = f2bfb(r.z * rs); ob.w = f2bfb(r.w * rs);
    *reinterpret_cast<ushort4*>(out + off) = ob;
}

// out = bf16(rms_norm(x)), x unmodified
__global__ __launch_bounds__(256) void norm_kernel(
    const float* __restrict__ x, unsigned short* __restrict__ out)
{
    int t = blockIdx.x;
    size_t off = (size_t)t * DM + threadIdx.x * 4;
    float4 r = *reinterpret_cast<const float4*>(x + off);
    float ss = r.x * r.x + r.y * r.y + r.z * r.z + r.w * r.w;
    float tot = block_sum256(ss);
    float rs = rsqrtf(tot / (float)DM + 1e-6f);
    ushort4 ob;
    ob.x = f2bfb(r.x * rs); ob.y = f2bfb(r.y * rs);
    ob.z = f2bfb(r.z * rs); ob.w = f2bfb(r.w * rs);
    *reinterpret_cast<ushort4*>(out + off) = ob;
}

// ---------- bf16-weight GEMM, m97 structure, 128x128 tile (row-major decode) ----------
// EPI 0: C bf16. EPI 1: relu(acc)^2 bf16. EPI 2: Cf fp32 += acc.
// EPI 3: fused QKV split; q/k get fused head-rms_norm+rope; v gets v1 copy/mix.
template <int EPI>
__global__ __launch_bounds__(256) void gemm_bb(
    const unsigned short* __restrict__ A, const unsigned short* __restrict__ Bw,
    unsigned short* __restrict__ Cb, float* __restrict__ Cf,
    unsigned short* __restrict__ Kb, unsigned short* __restrict__ Vb,
    const unsigned short* __restrict__ V1in, unsigned short* __restrict__ V1out,
    const float* __restrict__ lambp, const float2* __restrict__ tab,
    int NX, int K, int ldC)
{
    __shared__ unsigned short As[128 * 64];
    __shared__ unsigned short Bs[128 * 64];

    int nwg = gridDim.x;
    int orig = blockIdx.x;
    int qq = nwg >> 3, rr = nwg & 7;
    int xcd = orig & 7, rem = orig >> 3;
    int wg = (xcd < rr ? xcd * (qq + 1) : rr * (qq + 1) + (xcd - rr) * qq) + rem;
    int bx = wg % NX, by = wg / NX;
    int m0 = by * 128, n0 = bx * 128;

    int tid = threadIdx.x, lane = tid & 63, w = tid >> 6;
    int wr = w >> 1, wc = w & 1;
    int rsub = lane >> 3, sl = lane & 7;
    int ssrc = sl ^ rsub;           // inverse-swizzled source slot
    int fr = lane & 15, fh = lane >> 4;

    size_t arow[4], brow[4];
#pragma unroll
    for (int i = 0; i < 4; ++i) {
        int c = 4 * w + i;
        arow[i] = (size_t)(m0 + 8 * c + rsub) * K + ssrc * 8;
        brow[i] = (size_t)(n0 + 8 * c + rsub) * K + ssrc * 8;
    }

    f32x4 acc[4][4];
#pragma unroll
    for (int m = 0; m < 4; ++m)
#pragma unroll
        for (int n = 0; n < 4; ++n) acc[m][n] = 0.0f;

    int NT = K >> 6;
    for (int kt = 0; kt < NT; ++kt) {
        int kb = kt * 64;
#pragma unroll
        for (int i = 0; i < 4; ++i) {
            __builtin_amdgcn_global_load_lds((gas_t)(const void*)(A + arow[i] + kb),
                                             (las_t)(void*)(&As[(4 * w + i) * 512]), 16, 0, 0);
            __builtin_amdgcn_global_load_lds((gas_t)(const void*)(Bw + brow[i] + kb),
                                             (las_t)(void*)(&Bs[(4 * w + i) * 512]), 16, 0, 0);
        }
        __syncthreads();
#pragma unroll
        for (int kk = 0; kk < 2; ++kk) {
            int slot = kk * 4 + fh;
            bf16x8 af[4], bfv[4];
#pragma unroll
            for (int m = 0; m < 4; ++m) {
                int row = wr * 64 + m * 16 + fr;
                af[m] = *reinterpret_cast<const bf16x8*>(&As[row * 64 + ((slot ^ (row & 7)) << 3)]);
            }
#pragma unroll
            for (int n = 0; n < 4; ++n) {
                int row = wc * 64 + n * 16 + fr;
                bfv[n] = *reinterpret_cast<const bf16x8*>(&Bs[row * 64 + ((slot ^ (row & 7)) << 3)]);
            }
#pragma unroll
            for (int m = 0; m < 4; ++m)
#pragma unroll
                for (int n = 0; n < 4; ++n)
                    acc[m][n] = __builtin_amdgcn_mfma_f32_16x16x32_bf16(af[m], bfv[n], acc[m][n], 0, 0, 0);
        }
        __syncthreads();
    }

    int rb = m0 + wr * 64 + fh * 4;
    int cb = n0 + wc * 64 + fr;

    if constexpr (EPI == 3) {
        int mat = n0 >> 10;
        if (mat < 2) {
            // fused per-head rms_norm + rope for q (mat 0) / k (mat 1)
            unsigned short* outp = (mat == 0) ? Cb : Kb;
#pragma unroll
            for (int m = 0; m < 4; ++m) {
#pragma unroll
                for (int j = 0; j < 4; ++j) {
                    int gr = rb + m * 16 + j;
                    int s = gr & (SS - 1);
                    float ss = 0.0f;
#pragma unroll
                    for (int n = 0; n < 4; ++n) ss += acc[m][n][j] * acc[m][n][j];
                    ss += __shfl_xor(ss, 1, 64);
                    ss += __shfl_xor(ss, 2, 64);
                    ss += __shfl_xor(ss, 4, 64);
                    ss += __shfl_xor(ss, 8, 64);
                    float rsn = rsqrtf(ss * (1.0f / (float)HD) + 1e-6f);
                    float nv0 = acc[m][0][j] * rsn;
                    float nv1 = acc[m][1][j] * rsn;
                    float nv2 = acc[m][2][j] * rsn;
                    float nv3 = acc[m][3][j] * rsn;
                    float2 t0 = tab[s * 32 + fr];
                    float2 t1 = tab[s * 32 + fr + 16];
                    float o0 = nv0 * t0.x + nv2 * t0.y;
                    float o1 = nv1 * t1.x + nv3 * t1.y;
                    float o2 = nv2 * t0.x - nv0 * t0.y;
                    float o3 = nv3 * t1.x - nv1 * t1.y;
                    size_t rowo = (size_t)gr * DM + ((cb)&1023);
                    outp[rowo] = f2bfb(o0);
                    outp[rowo + 16] = f2bfb(o1);
                    outp[rowo + 32] = f2bfb(o2);
                    outp[rowo + 48] = f2bfb(o3);
                }
            }
        } else {
            // v path: copy (layer 0) or mix with v1
            float la = V1out ? 0.0f : *lambp;
#pragma unroll
            for (int n = 0; n < 4; ++n) {
                int gc = cb + n * 16;
#pragma unroll
                for (int m = 0; m < 4; ++m) {
#pragma unroll
                    for (int j = 0; j < 4; ++j) {
                        int gr = rb + m * 16 + j;
                        size_t o = (size_t)gr * DM + (gc & 1023);
                        unsigned short bv = f2bfb(acc[m][n][j]);
                        if (V1out) {
                            Vb[o] = bv;
                            V1out[o] = bv;
                        } else {
                            float mixed = (1.0f - la) * bfb2f(bv) + la * bfb2f(V1in[o]);
                            Vb[o] = f2bfb(mixed);
                        }
                    }
                }
            }
        }
        return;
    }

#pragma unroll
    for (int n = 0; n < 4; ++n) {
        int gc = cb + n * 16;
#pragma unroll
        for (int m = 0; m < 4; ++m) {
#pragma unroll
            for (int j = 0; j < 4; ++j) {
                int gr = rb + m * 16 + j;
                float val = acc[m][n][j];
                if constexpr (EPI == 0) {
                    Cb[(size_t)gr * ldC + gc] = f2bfb(val);
                } else if constexpr (EPI == 1) {
                    float rl = fmaxf(val, 0.0f);
                    Cb[(size_t)gr * ldC + gc] = f2bfb(rl * rl);
                } else if constexpr (EPI == 2) {
                    size_t o = (size_t)gr * ldC + gc;
                    Cf[o] = Cf[o] + val;
                }
            }
        }
    }
}

// ---------- lm_head GEMM (single-buffer), fused softcap+exp partial-sum ----------
// exp(softcap(z)-30) == exp(-60/(t+1)) with t = exp(z/15)   [exact identity]
__global__ __launch_bounds__(256) void gemm_lm(
    const unsigned short* __restrict__ A, const unsigned short* __restrict__ Bw,
    const int* __restrict__ target, float* __restrict__ part, float* __restrict__ zbf,
    int K)
{
    __shared__ unsigned short As[128 * 64];
    __shared__ unsigned short Bs[128 * 64];
    __shared__ float reds[2][2][64];

    // bijective xcd chunking: nwg = 4704 = 8 * 588
    int orig = blockIdx.x;
    int xcd = orig & 7, rank = orig >> 3;
    int e = xcd * 588 + rank;
    int g = 0;
#pragma unroll
    for (int it = 0; it < 7; ++it) {
        int sz = (g & 1) ? 584 : 592;
        if (e >= sz) { e -= sz; ++g; }
    }
    int nj = g & 1, mi = g >> 1;
    int bxl = e >> 3, byl = e & 7;
    int bx = nj * 74 + bxl;
    int by = mi * 8 + byl;
    int m0 = by * 128, n0 = bx * 128;

    int tid = threadIdx.x, lane = tid & 63, w = tid >> 6;
    int wr = w >> 1, wc = w & 1;
    int rsub = lane >> 3, sl = lane & 7;
    int ssrc = sl ^ rsub;
    int fr = lane & 15, fh = lane >> 4;

    size_t arow[4], brow[4];
#pragma unroll
    for (int i = 0; i < 4; ++i) {
        int c = 4 * w + i;
        arow[i] = (size_t)(m0 + 8 * c + rsub) * K + ssrc * 8;
        brow[i] = (size_t)(n0 + 8 * c + rsub) * K + ssrc * 8;
    }

    f32x4 acc[4][4];
#pragma unroll
    for (int m = 0; m < 4; ++m)
#pragma unroll
        for (int n = 0; n < 4; ++n) acc[m][n] = 0.0f;

    int NT = K >> 6;
    for (int kt = 0; kt < NT; ++kt) {
        int kb = kt * 64;
#pragma unroll
        for (int i = 0; i < 4; ++i) {
            __builtin_amdgcn_global_load_lds((gas_t)(const void*)(A + arow[i] + kb),
                                             (las_t)(void*)(&As[(4 * w + i) * 512]), 16, 0, 0);
            __builtin_amdgcn_global_load_lds((gas_t)(const void*)(Bw + brow[i] + kb),
                                             (las_t)(void*)(&Bs[(4 * w + i) * 512]), 16, 0, 0);
        }
        __syncthreads();
#pragma unroll
        for (int kk = 0; kk < 2; ++kk) {
            int slot = kk * 4 + fh;
            bf16x8 af[4], bfv[4];
#pragma unroll
            for (int m = 0; m < 4; ++m) {
                int row = wr * 64 + m * 16 + fr;
                af[m] = *reinterpret_cast<const bf16x8*>(&As[row * 64 + ((slot ^ (row & 7)) << 3)]);
            }
#pragma unroll
            for (int n = 0; n < 4; ++n) {
                int row = wc * 64 + n * 16 + fr;
                bfv[n] = *reinterpret_cast<const bf16x8*>(&Bs[row * 64 + ((slot ^ (row & 7)) << 3)]);
            }
#pragma unroll
            for (int m = 0; m < 4; ++m)
#pragma unroll
                for (int n = 0; n < 4; ++n)
                    acc[m][n] = __builtin_amdgcn_mfma_f32_16x16x32_bf16(af[m], bfv[n], acc[m][n], 0, 0, 0);
        }
        __syncthreads();
    }

    int rb = m0 + wr * 64 + fh * 4;
    int cb = n0 + wc * 64 + fr;
#pragma unroll
    for (int m = 0; m < 4; ++m) {
#pragma unroll
        for (int j = 0; j < 4; ++j) {
            int gr = rb + m * 16 + j;
            int tg = target[gr];
            float rs = 0.0f;
#pragma unroll
            for (int n = 0; n < 4; ++n) {
                int gc = cb + n * 16;
                if (gc < VV) {
                    float zv = acc[m][n][j];
                    float tt = __expf(zv * 0.066666667f);     // exp(z/15)
                    rs += __expf(__fdividef(-60.0f, tt + 1.0f));
                    if (gc == tg) zbf[gr] = 30.0f - 60.0f / (tt + 1.0f);
                }
            }
            rs += __shfl_xor(rs, 1, 64);
            rs += __shfl_xor(rs, 2, 64);
            rs += __shfl_xor(rs, 4, 64);
            rs += __shfl_xor(rs, 8, 64);
            if (fr == 0) reds[wr][wc][m * 16 + fh * 4 + j] = rs;
        }
    }
    __syncthreads();
    if (tid < 128) {
        int wrx = tid >> 6, r64 = tid & 63;
        part[(size_t)(m0 + tid) * NXLM + bx] = reds[wrx][0][r64] + reds[wrx][1][r64];
    }
}

// merge NXLM partial sums per token -> loss = 30 + log(sum) - z_target
__global__ __launch_bounds__(256) void loss_merge_kernel(
    const float* __restrict__ part, const float* __restrict__ zbf,
    const int* __restrict__ target, float* __restrict__ out)
{
    int t = blockIdx.x;
    float l = 0.0f;
    for (int i = threadIdx.x; i < NXLM; i += 256) l += part[(size_t)t * NXLM + i];
    l = block_sum256(l);
    if (threadIdx.x == 0) {
        int tg = target[t];
        float lse = 30.0f + logf(l);
        bool masked = (tg == 16384) || (tg == 18433) || (tg == 18690);
        out[t] = masked ? 0.0f : (lse - zbf[t]);
    }
}

// ---------- BM=64 variant for small-N / high-parallelism GEMMs (wo, w1, w2) ----------
template <int EPI>
__global__ __launch_bounds__(256) void gemm_bb64(
    const unsigned short* __restrict__ A, const unsigned short* __restrict__ Bw,
    unsigned short* __restrict__ Cb, float* __restrict__ Cf,
    int NX, int K, int ldC)
{
    __shared__ unsigned short As[64 * 64];
    __shared__ unsigned short Bs[128 * 64];

    int nwg = gridDim.x;
    int orig = blockIdx.x;
    int qq = nwg >> 3, rr = nwg & 7;
    int xcd = orig & 7, rem = orig >> 3;
    int wg = (xcd < rr ? xcd * (qq + 1) : rr * (qq + 1) + (xcd - rr) * qq) + rem;
    int bx = wg % NX, by = wg / NX;
    int m0 = by * 64, n0 = bx * 128;

    int tid = threadIdx.x, lane = tid & 63, w = tid >> 6;
    int wr = w >> 1, wc = w & 1;
    int rsub = lane >> 3, sl = lane & 7;
    int ssrc = sl ^ rsub;
    int fr = lane & 15, fh = lane >> 4;

    size_t arow[2], brow[4];
#pragma unroll
    for (int i = 0; i < 2; ++i) {
        int c = 2 * w + i;
        arow[i] = (size_t)(m0 + 8 * c + rsub) * K + ssrc * 8;
    }
#pragma unroll
    for (int i = 0; i < 4; ++i) {
        int c = 4 * w + i;
        brow[i] = (size_t)(n0 + 8 * c + rsub) * K + ssrc * 8;
    }

    f32x4 acc[2][4];
#pragma unroll
    for (int m = 0; m < 2; ++m)
#pragma unroll
        for (int n = 0; n < 4; ++n) acc[m][n] = 0.0f;

    int NT = K >> 6;
    for (int kt = 0; kt < NT; ++kt) {
        int kb = kt * 64;
#pragma unroll
        for (int i = 0; i < 2; ++i)
            __builtin_amdgcn_global_load_lds((gas_t)(const void*)(A + arow[i] + kb),
                                             (las_t)(void*)(&As[(2 * w + i) * 512]), 16, 0, 0);
#pragma unroll
        for (int i = 0; i < 4; ++i)
            __builtin_amdgcn_global_load_lds((gas_t)(const void*)(Bw + brow[i] + kb),
                                             (las_t)(void*)(&Bs[(4 * w + i) * 512]), 16, 0, 0);
        __syncthreads();
#pragma unroll
        for (int kk = 0; kk < 2; ++kk) {
            int slot = kk * 4 + fh;
            bf16x8 af[2], bfv[4];
#pragma unroll
            for (int m = 0; m < 2; ++m) {
                int row = wr * 32 + m * 16 + fr;
                af[m] = *reinterpret_cast<const bf16x8*>(&As[row * 64 + ((slot ^ (row & 7)) << 3)]);
            }
#pragma unroll
            for (int n = 0; n < 4; ++n) {
                int row = wc * 64 + n * 16 + fr;
                bfv[n] = *reinterpret_cast<const bf16x8*>(&Bs[row * 64 + ((slot ^ (row & 7)) << 3)]);
            }
#pragma unroll
            for (int m = 0; m < 2; ++m)
#pragma unroll
                for (int n = 0; n < 4; ++n)
                    acc[m][n] = __builtin_amdgcn_mfma_f32_16x16x32_bf16(af[m], bfv[n], acc[m][n], 0, 0, 0);
        }
        __syncthreads();
    }

    int rb = m0 + wr * 32 + fh * 4;
    int cb = n0 + wc * 64 + fr;
#pragma unroll
    for (int n = 0; n < 4; ++n) {
        int gc = cb + n * 16;
#pragma unroll
        for (int m = 0; m < 2; ++m) {
#pragma unroll
            for (int j = 0; j < 4; ++j) {
                int gr = rb + m * 16 + j;
                float val = acc[m][n][j];
                if constexpr (EPI == 0) {
                    Cb[(size_t)gr * ldC + gc] = f2bfb(val);
                } else if constexpr (EPI == 1) {
                    float rl = fmaxf(val, 0.0f);
                    Cb[(size_t)gr * ldC + gc] = f2bfb(rl * rl);
                } else {
                    size_t o = (size_t)gr * ldC + gc;
                    Cf[o] = Cf[o] + val;
                }
            }
        }
    }
}

// MFMA flash attention, mask-sparse: local sliding-window pass + packed level>0 pass.
__global__ __launch_bounds__(256) void attn_mfma_kernel(
    const unsigned short* __restrict__ q, const unsigned short* __restrict__ k,
    const unsigned short* __restrict__ v,
    const unsigned short* __restrict__ kp, const unsigned short* __restrict__ vp,
    const int* __restrict__ gpos, const int* __restrict__ nbuf,
    unsigned short* __restrict__ y)
{
    __shared__ unsigned short Qs[64][APITCH];
    __shared__ unsigned short Ks[64][APITCH];
    __shared__ unsigned short Vt[64][APITCH];
    __shared__ unsigned short Ps[64][APITCH];
    __shared__ int posS[64];

    int bh = blockIdx.x;
    int b = bh >> 4, h = bh & 15;
    int q0 = blockIdx.y * 64;
    size_t base = (size_t)b * SS * DM + h * HD;
    int tid = threadIdx.x;
    int lane = tid & 63, w = tid >> 6;
    int srow = tid >> 2, sc = tid & 3;

    {
        const unsigned short* src = q + base + (size_t)(q0 + srow) * DM;
        *reinterpret_cast<uint4*>(&Qs[srow][sc * 8]) = *reinterpret_cast<const uint4*>(src + sc * 8);
        *reinterpret_cast<uint4*>(&Qs[srow][(sc + 4) * 8]) = *reinterpret_cast<const uint4*>(src + (sc + 4) * 8);
    }
    __syncthreads();

    int fr = lane & 15, fc = (lane >> 4) * 8;
    int rj = (lane >> 4) * 4;

    bf16x8 qa[2];
    qa[0] = *reinterpret_cast<const bf16x8*>(&Qs[w * 16 + fr][fc]);
    qa[1] = *reinterpret_cast<const bf16x8*>(&Qs[w * 16 + fr][32 + fc]);

    float mreg[4], lreg[4];
    f32x4 yacc[4];
#pragma unroll
    for (int j = 0; j < 4; ++j) { mreg[j] = -1e30f; lreg[j] = 0.0f; yacc[j] = 0.0f; }

    int nbp = nbuf[BBATCH + b];

    int t0 = (q0 >= 256) ? ((q0 - 256) >> 6) : 0;
    int t1 = q0 >> 6;
    for (int pass = 0; pass < 2; ++pass) {
        int kt_begin = (pass == 0) ? t0 : 0;
        int kt_end = (pass == 0) ? (t1 + 1) : (nbp >> 6);
        for (int kt = kt_begin; kt < kt_end; ++kt) {
            int k0 = kt * 64;
            if (pass == 1) {
                if (gpos[b * SS + k0] > q0 - 194) break;
            }
            __syncthreads();
            {
                const unsigned short* ksrc = (pass == 0) ? (k + base) : (kp + base);
                const unsigned short* vsrc = (pass == 0) ? (v + base) : (vp + base);
                size_t goff = (size_t)(k0 + srow) * DM;
                uint4 kv0 = *reinterpret_cast<const uint4*>(ksrc + goff + sc * 8);
                uint4 kv1 = *reinterpret_cast<const uint4*>(ksrc + goff + (sc + 4) * 8);
                *reinterpret_cast<uint4*>(&Ks[srow][sc * 8]) = kv0;
                *reinterpret_cast<uint4*>(&Ks[srow][(sc + 4) * 8]) = kv1;
                uint4 vv0 = *reinterpret_cast<const uint4*>(vsrc + goff + sc * 8);
                uint4 vv1 = *reinterpret_cast<const uint4*>(vsrc + goff + (sc + 4) * 8);
                const unsigned short* e0 = reinterpret_cast<const unsigned short*>(&vv0);
                const unsigned short* e1 = reinterpret_cast<const unsigned short*>(&vv1);
#pragma unroll
                for (int i = 0; i < 8; ++i) Vt[sc * 8 + i][srow] = e0[i];
#pragma unroll
                for (int i = 0; i < 8; ++i) Vt[(sc + 4) * 8 + i][srow] = e1[i];
                if (pass == 1 && tid < 64) posS[tid] = gpos[b * SS + k0 + tid];
            }
            __syncthreads();

            f32x4 sacc[4];
#pragma unroll
            for (int n = 0; n < 4; ++n) {
                bf16x8 kb0 = *reinterpret_cast<const bf16x8*>(&Ks[n * 16 + fr][fc]);
                bf16x8 kb1 = *reinterpret_cast<const bf16x8*>(&Ks[n * 16 + fr][32 + fc]);
                f32x4 a = {0.0f, 0.0f, 0.0f, 0.0f};
                a = __builtin_amdgcn_mfma_f32_16x16x32_bf16(qa[0], kb0, a, 0, 0, 0);
                a = __builtin_amdgcn_mfma_f32_16x16x32_bf16(qa[1], kb1, a, 0, 0, 0);
                sacc[n] = a;
            }

            float sm[4][4];
            float cm[4] = {-1e30f, -1e30f, -1e30f, -1e30f};
#pragma unroll
            for (int n = 0; n < 4; ++n) {
                int kg = (pass == 0) ? (k0 + n * 16 + fr) : posS[n * 16 + fr];
#pragma unroll
                for (int j = 0; j < 4; ++j) {
                    int qg = q0 + w * 16 + rj + j;
                    bool valid = (pass == 0) ? ((kg <= qg) && (qg - kg <= 256))
                                             : (kg < qg - 256);
                    float s = valid ? sacc[n][j] * 0.125f : -1e30f;
                    sm[n][j] = s;
                    cm[j] = fmaxf(cm[j], s);
                }
            }
#pragma unroll
            for (int j = 0; j < 4; ++j) {
                cm[j] = fmaxf(cm[j], __shfl_xor(cm[j], 1, 64));
                cm[j] = fmaxf(cm[j], __shfl_xor(cm[j], 2, 64));
                cm[j] = fmaxf(cm[j], __shfl_xor(cm[j], 4, 64));
                cm[j] = fmaxf(cm[j], __shfl_xor(cm[j], 8, 64));
            }
            float sj[4], ps[4];
#pragma unroll
            for (int j = 0; j < 4; ++j) {
                float nm = fmaxf(mreg[j], cm[j]);
                sj[j] = __expf(mreg[j] - nm);
                mreg[j] = nm;
                ps[j] = 0.0f;
            }
#pragma unroll
            for (int n = 0; n < 4; ++n) {
#pragma unroll
                for (int j = 0; j < 4; ++j) {
                    float p = (sm[n][j] > -1e29f) ? __expf(sm[n][j] - mreg[j]) : 0.0f;
                    Ps[w * 16 + rj + j][n * 16 + fr] = f2bfb(p);
                    ps[j] += p;
                }
            }
#pragma unroll
            for (int j = 0; j < 4; ++j) {
                float t = ps[j];
                t += __shfl_xor(t, 1, 64); t += __shfl_xor(t, 2, 64);
                t += __shfl_xor(t, 4, 64); t += __shfl_xor(t, 8, 64);
                lreg[j] = lreg[j] * sj[j] + t;
            }
#pragma unroll
            for (int n = 0; n < 4; ++n)
#pragma unroll
                for (int j = 0; j < 4; ++j) yacc[n][j] *= sj[j];

            bf16x8 pa0 = *reinterpret_cast<const bf16x8*>(&Ps[w * 16 + fr][fc]);
            bf16x8 pa1 = *reinterpret_cast<const bf16x8*>(&Ps[w * 16 + fr][32 + fc]);
#pragma unroll
            for (int n = 0; n < 4; ++n) {
                bf16x8 vb0 = *reinterpret_cast<const bf16x8*>(&Vt[n * 16 + fr][fc]);
                bf16x8 vb1 = *reinterpret_cast<const bf16x8*>(&Vt[n * 16 + fr][32 + fc]);
                yacc[n] = __builtin_amdgcn_mfma_f32_16x16x32_bf16(pa0, vb0, yacc[n], 0, 0, 0);
                yacc[n] = __builtin_amdgcn_mfma_f32_16x16x32_bf16(pa1, vb1, yacc[n], 0, 0, 0);
            }
        }
    }

    float inv[4];
#pragma unroll
    for (int j = 0; j < 4; ++j) inv[j] = 1.0f / lreg[j];
#pragma unroll
    for (int n = 0; n < 4; ++n) {
#pragma unroll
        for (int j = 0; j < 4; ++j) {
            int qg = q0 + w * 16 + rj + j;
            y[base + (size_t)qg * DM + n * 16 + fr] = f2bfb(yacc[n][j] * inv[j]);
        }
    }
}

extern "C" void kernel_launch(void* const* d_in, const int* in_sizes, int n_in,
                              void* d_out, int out_size, void* d_ws, size_t ws_size,
                              hipStream_t stream)
{
    const int* idx = (const int*)d_in[0];
    const int* target = (const int*)d_in[1];
    const float* wte = (const float*)d_in[2];
    const float* lambdas = (const float*)d_in[3];
    const float* lamb = (const float*)d_in[4];
    const float* wq = (const float*)d_in[5];
    const float* wk = (const float*)d_in[6];
    const float* wv = (const float*)d_in[7];
    const float* wo = (const float*)d_in[8];
    const float* w1 = (const float*)d_in[9];
    const float* w2 = (const float*)d_in[10];
    const float* lm_head = (const float*)d_in[11];
    float* out = (float*)d_out;

    char* ws = (char*)d_ws;
    const size_t MB = (size_t)1 << 20;
    float* x            = (float*)(ws);
    unsigned short* x0  = (unsigned short*)(ws + 16 * MB);
    unsigned short* nrm = (unsigned short*)(ws + 24 * MB);
    unsigned short* qb  = (unsigned short*)(ws + 32 * MB);
    unsigned short* kb  = (unsigned short*)(ws + 40 * MB);
    unsigned short* vb  = (unsigned short*)(ws + 48 * MB);
    unsigned short* v1b = (unsigned short*)(ws + 56 * MB);
    unsigned short* yb  = (unsigned short*)(ws + 64 * MB);
    unsigned short* hid = (unsigned short*)(ws + 72 * MB);   // 32 MB; dead during attention & lm
    unsigned short* kp  = (unsigned short*)(ws + 72 * MB);   // packed K (8 MB), overlaps hid
    unsigned short* vp  = (unsigned short*)(ws + 80 * MB);   // packed V (8 MB), overlaps hid
    float* part         = (float*)(ws + 72 * MB);            // lm partials (2.4 MB), lm-time only
    float* zbf          = (float*)(ws + 78 * MB);            // lm target logit (16 KB), lm-time only
    int* levels         = (int*)(ws + 104 * MB);
    int* gpos           = (int*)(ws + 104 * MB + 64 * 1024);
    int* nbuf           = (int*)(ws + 104 * MB + 128 * 1024);
    float2* ropetab     = (float2*)(ws + 104 * MB + 256 * 1024); // 512 KB, persistent
    unsigned short* wqkvb = (unsigned short*)(ws + 105 * MB); // [NL][3][1024][1024]
    unsigned short* wob = (unsigned short*)(ws + 129 * MB);
    unsigned short* w1b = (unsigned short*)(ws + 137 * MB);
    unsigned short* w2b = (unsigned short*)(ws + 169 * MB);
    unsigned short* lmb = (unsigned short*)(ws + 201 * MB);
    bool cvt = ws_size >= 238 * MB;

    if (cvt) {
        int n1 = DM * DM;
        int nff = NL * FFD * DM;
        for (int i = 0; i < NL; ++i) {
            cvtw_kernel<<<n1 / 1024, 256, 0, stream>>>(wq + (size_t)i * n1, wqkvb + ((size_t)i * 3 + 0) * n1, n1);
            cvtw_kernel<<<n1 / 1024, 256, 0, stream>>>(wk + (size_t)i * n1, wqkvb + ((size_t)i * 3 + 1) * n1, n1);
            cvtw_kernel<<<n1 / 1024, 256, 0, stream>>>(wv + (size_t)i * n1, wqkvb + ((size_t)i * 3 + 2) * n1, n1);
        }
        cvtw_kernel<<<NL * n1 / 1024, 256, 0, stream>>>(wo, wob, NL * n1);
        cvtw_kernel<<<nff / 1024, 256, 0, stream>>>(w1, w1b, nff);
        cvtw_kernel<<<nff / 1024, 256, 0, stream>>>(w2, w2b, nff);
        cvtpad_kernel<<<(VP * DM) / 1024, 256, 0, stream>>>(lm_head, lmb, VV * DM, VP * DM);
    }
    ropetab_kernel<<<SS / 8, 256, 0, stream>>>(ropetab);

    embed_kernel<<<TT, 256, 0, stream>>>(idx, wte, x, x0, levels);
    pack_kernel<<<BBATCH, 256, 0, stream>>>(levels, gpos, nbuf);

    for (int i = 0; i < NL; ++i) {
        mixnorm_kernel<<<TT, 256, 0, stream>>>(x, x0, lambdas + 2 * i, nrm);
        if (cvt) {
            if (i == 0)
                gemm_bb<3><<<768, 256, 0, stream>>>(nrm, wqkvb + (size_t)i * 3 * DM * DM,
                                                    qb, nullptr, kb, vb, nullptr, v1b, nullptr, ropetab, 24, DM, DM);
            else
                gemm_bb<3><<<768, 256, 0, stream>>>(nrm, wqkvb + (size_t)i * 3 * DM * DM,
                                                    qb, nullptr, kb, vb, v1b, nullptr, lamb + i, ropetab, 24, DM, DM);
        }
        gather_kernel<<<BBATCH * SS, 64, 0, stream>>>(kb, vb, gpos, nbuf, kp, vp);
        attn_mfma_kernel<<<dim3(BBATCH * NH, SS / 64), 256, 0, stream>>>(qb, kb, vb, kp, vp, gpos, nbuf, yb);
        if (cvt) {
            gemm_bb64<2><<<512, 256, 0, stream>>>(yb, wob + (size_t)i * DM * DM, nullptr, x, 8, DM, DM);
            norm_kernel<<<TT, 256, 0, stream>>>(x, nrm);
            gemm_bb64<1><<<2048, 256, 0, stream>>>(nrm, w1b + (size_t)i * FFD * DM, hid, nullptr, 32, DM, FFD);
            gemm_bb64<2><<<512, 256, 0, stream>>>(hid, w2b + (size_t)i * DM * FFD, nullptr, x, 8, FFD, DM);
        }
    }

    norm_kernel<<<TT, 256, 0, stream>>>(x, nrm);
    gemm_lm<<<NXLM * 32, 256, 0, stream>>>(nrm, lmb, target, part, zbf, DM);
    loss_merge_kernel<<<TT, 256, 0, stream>>>(part, zbf, target, out);
}

// Round 17
// 1305.538 us; speedup vs baseline: 1.1267x; 1.0958x over previous
//
#include <hip/hip_runtime.h>
#include <hip/hip_bf16.h>

#define TT 4096
#define SS 2048
#define BBATCH 2
#define DM 1024
#define NH 16
#define HD 64
#define FFD 4096
#define NL 4
#define VV 18691
#define VP 18816
#define APITCH 72
#define NXLM 147
#define SENT 0x3FFFFFFF

typedef __bf16 bf16x8 __attribute__((ext_vector_type(8)));
typedef float f32x4 __attribute__((ext_vector_type(4)));
typedef const __attribute__((address_space(1))) void* gas_t;
typedef __attribute__((address_space(3))) void* las_t;

__device__ __forceinline__ float bfb2f(unsigned short u) {
    union { unsigned int i; float f; } x;
    x.i = ((unsigned int)u) << 16;
    return x.f;
}
__device__ __forceinline__ unsigned short f2bfb(float f) {
    union { float f; unsigned int i; } x;
    x.f = f;
    unsigned int r = 0x7fffu + ((x.i >> 16) & 1u);
    x.i += r;
    return (unsigned short)(x.i >> 16);
}

__device__ __forceinline__ float wave_sum(float v) {
#pragma unroll
    for (int o = 32; o; o >>= 1) v += __shfl_xor(v, o, 64);
    return v;
}

__device__ __forceinline__ float block_sum256(float v) {
    __shared__ float sb[4];
    v = wave_sum(v);
    int wid = threadIdx.x >> 6;
    if ((threadIdx.x & 63) == 0) sb[wid] = v;
    __syncthreads();
    float t = sb[0] + sb[1] + sb[2] + sb[3];
    __syncthreads();
    return t;
}

// ---- weight fp32 -> bf16 conversion ----
__global__ __launch_bounds__(256) void cvtw_kernel(const float* __restrict__ src,
                                                   unsigned short* __restrict__ dst, int n)
{
    int i = (blockIdx.x * 256 + threadIdx.x) * 4;
    if (i >= n) return;
    float4 f = *reinterpret_cast<const float4*>(src + i);
    ushort4 u;
    u.x = f2bfb(f.x); u.y = f2bfb(f.y); u.z = f2bfb(f.z); u.w = f2bfb(f.w);
    *reinterpret_cast<ushort4*>(dst + i) = u;
}

__global__ __launch_bounds__(256) void cvtpad_kernel(const float* __restrict__ src,
                                                     unsigned short* __restrict__ dst,
                                                     int nreal, int ntot)
{
    int i = (blockIdx.x * 256 + threadIdx.x) * 4;
    if (i >= ntot) return;
    ushort4 u = {0, 0, 0, 0};
    if (i < nreal) {
        float4 f = *reinterpret_cast<const float4*>(src + i);
        u.x = f2bfb(f.x); u.y = f2bfb(f.y); u.z = f2bfb(f.z); u.w = f2bfb(f.w);
    }
    *reinterpret_cast<ushort4*>(dst + i) = u;
}

// rope cos/sin table: tab[s][j] = (cos, sin)(s * 10000^(-j/32))
__global__ __launch_bounds__(256) void ropetab_kernel(float2* __restrict__ tab)
{
    int s = blockIdx.x * 8 + (threadIdx.x >> 5);
    int j = threadIdx.x & 31;
    float invf = exp2f(-(float)j * 0.41524101186092025f);
    float ang = (float)s * invf;
    float sn, cs;
    sincosf(ang, &sn, &cs);
    tab[s * 32 + j] = make_float2(cs, sn);
}

// x = rms_norm(wte[idx]); x0 = bf16(x); levels[t]
__global__ __launch_bounds__(256) void embed_kernel(
    const int* __restrict__ idx, const float* __restrict__ wte,
    float* __restrict__ x, unsigned short* __restrict__ x0, int* __restrict__ levels)
{
    int t = blockIdx.x;
    int id = idx[t];
    const float* row = wte + (size_t)id * DM;
    float4 v = *reinterpret_cast<const float4*>(row + threadIdx.x * 4);
    float ss = v.x * v.x + v.y * v.y + v.z * v.z + v.w * v.w;
    float tot = block_sum256(ss);
    float rs = rsqrtf(tot / (float)DM + 1e-6f);
    float4 o;
    o.x = v.x * rs; o.y = v.y * rs; o.z = v.z * rs; o.w = v.w * rs;
    size_t off = (size_t)t * DM + threadIdx.x * 4;
    *reinterpret_cast<float4*>(x + off) = o;
    ushort4 ub;
    ub.x = f2bfb(o.x); ub.y = f2bfb(o.y); ub.z = f2bfb(o.z); ub.w = f2bfb(o.w);
    *reinterpret_cast<ushort4*>(x0 + off) = ub;
    if (threadIdx.x == 0) levels[t] = (id >= 16385) + (id >= 18434);
}

// per-batch ascending list of positions with level>0
__global__ __launch_bounds__(256) void pack_kernel(
    const int* __restrict__ levels, int* __restrict__ gpos, int* __restrict__ nbuf)
{
    int b = blockIdx.x;
    const int* lv = levels + b * SS;
    int* gp = gpos + b * SS;
    __shared__ int wsum[4];
    __shared__ int base;
    if (threadIdx.x == 0) base = 0;
    __syncthreads();
    int lane = threadIdx.x & 63, w = threadIdx.x >> 6;
    for (int c = 0; c < SS; c += 256) {
        int s = c + threadIdx.x;
        int flag = (lv[s] > 0) ? 1 : 0;
        unsigned long long mask = __ballot(flag);
        int pre = __popcll(mask & ((1ull << lane) - 1ull));
        int wtot = __popcll(mask);
        if (lane == 0) wsum[w] = wtot;
        __syncthreads();
        int woff = 0;
#pragma unroll
        for (int i = 0; i < 4; ++i) if (i < w) woff += wsum[i];
        int tot = wsum[0] + wsum[1] + wsum[2] + wsum[3];
        int mybase = base;
        if (flag) gp[mybase + woff + pre] = s;
        __syncthreads();
        if (threadIdx.x == 0) base += tot;
        __syncthreads();
    }
    int nb = base;
    int nbp = (nb + 63) & ~63;
    for (int i = nb + threadIdx.x; i < SS; i += 256) gp[i] = SENT;
    if (threadIdx.x == 0) { nbuf[b] = nb; nbuf[BBATCH + b] = nbp; }
}

// gather roped K and mixed V rows of level>0 positions into packed buffers (4 rows/block)
__global__ __launch_bounds__(256) void gather_kernel(
    const unsigned short* __restrict__ kb, const unsigned short* __restrict__ vb,
    const int* __restrict__ gpos, const int* __restrict__ nbuf,
    unsigned short* __restrict__ kp, unsigned short* __restrict__ vp)
{
    int gid = blockIdx.x * 4 + (threadIdx.x >> 6);
    int b = gid >> 11;
    int j = gid & (SS - 1);
    if (j >= nbuf[BBATCH + b]) return;
    int pos = gpos[b * SS + j];
    int lane = threadIdx.x & 63;
    size_t dst = ((size_t)b * SS + j) * DM + lane * 16;
    if (pos < SS) {
        size_t src = ((size_t)b * SS + pos) * DM + lane * 16;
        *reinterpret_cast<uint4*>(kp + dst) = *reinterpret_cast<const uint4*>(kb + src);
        *reinterpret_cast<uint4*>(kp + dst + 8) = *reinterpret_cast<const uint4*>(kb + src + 8);
        *reinterpret_cast<uint4*>(vp + dst) = *reinterpret_cast<const uint4*>(vb + src);
        *reinterpret_cast<uint4*>(vp + dst + 8) = *reinterpret_cast<const uint4*>(vb + src + 8);
    } else {
        uint4 z = {0, 0, 0, 0};
        *reinterpret_cast<uint4*>(kp + dst) = z;
        *reinterpret_cast<uint4*>(kp + dst + 8) = z;
        *reinterpret_cast<uint4*>(vp + dst) = z;
        *reinterpret_cast<uint4*>(vp + dst + 8) = z;
    }
}

// xr = l0*x + l1*x0 (written back to x); out = bf16(rms_norm(xr))
__global__ __launch_bounds__(256) void mixnorm_kernel(
    float* __restrict__ x, const unsigned short* __restrict__ x0,
    const float* __restrict__ lam2, unsigned short* __restrict__ out)
{
    int t = blockIdx.x;
    size_t off = (size_t)t * DM + threadIdx.x * 4;
    float4 xv = *reinterpret_cast<const float4*>(x + off);
    float l0 = lam2[0], l1 = lam2[1];
    ushort4 u = *reinterpret_cast<const ushort4*>(x0 + off);
    float4 r;
    r.x = l0 * xv.x + l1 * bfb2f(u.x);
    r.y = l0 * xv.y + l1 * bfb2f(u.y);
    r.z = l0 * xv.z + l1 * bfb2f(u.z);
    r.w = l0 * xv.w + l1 * bfb2f(u.w);
    float ss = r.x * r.x + r.y * r.y + r.z * r.z + r.w * r.w;
    float tot = block_sum256(ss);
    float rs = rsqrtf(tot / (float)DM + 1e-6f);
    *reinterpret_cast<float4*>(x + off) = r;
    ushort4 ob;
    ob.x = f2bfb(r.x * rs); ob.y = f2bfb(r.y * rs);
    ob.z = f2bfb(r.z * rs); ob.w = f2bfb(r.w * rs);
    *reinterpret_cast<ushort4*>(out + off) = ob;
}

// out = bf16(rms_norm(x)), x unmodified
__global__ __launch_bounds__(256) void norm_kernel(
    const float* __restrict__ x, unsigned short* __restrict__ out)
{
    int t = blockIdx.x;
    size_t off = (size_t)t * DM + threadIdx.x * 4;
    float4 r = *reinterpret_cast<const float4*>(x + off);
    float ss = r.x * r.x + r.y * r.y + r.z * r.z + r.w * r.w;
    float tot = block_sum256(ss);
    float rs = rsqrtf(tot / (float)DM + 1e-6f);
    ushort4 ob;
    ob.x = f2bfb(r.x * rs); ob.y = f2bfb(r.y * rs);
    ob.z = f2bfb(r.z * rs); ob.w = f2bfb(r.w * rs);
    *reinterpret_cast<ushort4*>(out + off) = ob;
}

// x += p0+p1 (bf16 partials); then mix with x0 (if domix) ; out = bf16(rms_norm)
__global__ __launch_bounds__(256) void w2mix_kernel(
    float* __restrict__ x, const unsigned short* __restrict__ p0,
    const unsigned short* __restrict__ p1, const unsigned short* __restrict__ x0,
    const float* __restrict__ lam2, unsigned short* __restrict__ out, int domix)
{
    int t = blockIdx.x;
    size_t off = (size_t)t * DM + threadIdx.x * 4;
    float4 xv = *reinterpret_cast<const float4*>(x + off);
    ushort4 a = *reinterpret_cast<const ushort4*>(p0 + off);
    ushort4 b = *reinterpret_cast<const ushort4*>(p1 + off);
    float4 r;
    r.x = xv.x + bfb2f(a.x) + bfb2f(b.x);
    r.y = xv.y + bfb2f(a.y) + bfb2f(b.y);
    r.z = xv.z + bfb2f(a.z) + bfb2f(b.z);
    r.w = xv.w + bfb2f(a.w) + bfb2f(b.w);
    if (domix) {
        float l0 = lam2[0], l1 = lam2[1];
        ushort4 u = *reinterpret_cast<const ushort4*>(x0 + off);
        r.x = l0 * r.x + l1 * bfb2f(u.x);
        r.y = l0 * r.y + l1 * bfb2f(u.y);
        r.z = l0 * r.z + l1 * bfb2f(u.z);
        r.w = l0 * r.w + l1 * bfb2f(u.w);
        *reinterpret_cast<float4*>(x + off) = r;
    }
    float ss = r.x * r.x + r.y * r.y + r.z * r.z + r.w * r.w;
    float tot = block_sum256(ss);
    float rs = rsqrtf(tot / (float)DM + 1e-6f);
    ushort4 ob;
    ob.x = f2bfb(r.x * rs); ob.y = f2bfb(r.y * rs);
    ob.z = f2bfb(r.z * rs); ob.w = f2bfb(r.w * rs);
    *reinterpret_cast<ushort4*>(out + off) = ob;
}

// ---------- bf16-weight GEMM, m97 structure, 128x128 tile (row-major decode) ----------
// EPI 0: C bf16. EPI 1: relu(acc)^2 bf16. EPI 2: Cf fp32 += acc.
// EPI 3: fused QKV split; q/k get fused head-rms_norm+rope; v gets v1 copy/mix.
template <int EPI>
__global__ __launch_bounds__(256) void gemm_bb(
    const unsigned short* __restrict__ A, const unsigned short* __restrict__ Bw,
    unsigned short* __restrict__ Cb, float* __restrict__ Cf,
    unsigned short* __restrict__ Kb, unsigned short* __restrict__ Vb,
    const unsigned short* __restrict__ V1in, unsigned short* __restrict__ V1out,
    const float* __restrict__ lambp, const float2* __restrict__ tab,
    int NX, int K, int ldC)
{
    __shared__ unsigned short As[128 * 64];
    __shared__ unsigned short Bs[128 * 64];

    int nwg = gridDim.x;
    int orig = blockIdx.x;
    int qq = nwg >> 3, rr = nwg & 7;
    int xcd = orig & 7, rem = orig >> 3;
    int wg = (xcd < rr ? xcd * (qq + 1) : rr * (qq + 1) + (xcd - rr) * qq) + rem;
    int bx = wg % NX, by = wg / NX;
    int m0 = by * 128, n0 = bx * 128;

    int tid = threadIdx.x, lane = tid & 63, w = tid >> 6;
    int wr = w >> 1, wc = w & 1;
    int rsub = lane >> 3, sl = lane & 7;
    int ssrc = sl ^ rsub;           // inverse-swizzled source slot
    int fr = lane & 15, fh = lane >> 4;

    size_t arow[4], brow[4];
#pragma unroll
    for (int i = 0; i < 4; ++i) {
        int c = 4 * w + i;
        arow[i] = (size_t)(m0 + 8 * c + rsub) * K + ssrc * 8;
        brow[i] = (size_t)(n0 + 8 * c + rsub) * K + ssrc * 8;
    }

    f32x4 acc[4][4];
#pragma unroll
    for (int m = 0; m < 4; ++m)
#pragma unroll
        for (int n = 0; n < 4; ++n) acc[m][n] = 0.0f;

    int NT = K >> 6;
    for (int kt = 0; kt < NT; ++kt) {
        int kb = kt * 64;
#pragma unroll
        for (int i = 0; i < 4; ++i) {
            __builtin_amdgcn_global_load_lds((gas_t)(const void*)(A + arow[i] + kb),
                                             (las_t)(void*)(&As[(4 * w + i) * 512]), 16, 0, 0);
            __builtin_amdgcn_global_load_lds((gas_t)(const void*)(Bw + brow[i] + kb),
                                             (las_t)(void*)(&Bs[(4 * w + i) * 512]), 16, 0, 0);
        }
        __syncthreads();
#pragma unroll
        for (int kk = 0; kk < 2; ++kk) {
            int slot = kk * 4 + fh;
            bf16x8 af[4], bfv[4];
#pragma unroll
            for (int m = 0; m < 4; ++m) {
                int row = wr * 64 + m * 16 + fr;
                af[m] = *reinterpret_cast<const bf16x8*>(&As[row * 64 + ((slot ^ (row & 7)) << 3)]);
            }
#pragma unroll
            for (int n = 0; n < 4; ++n) {
                int row = wc * 64 + n * 16 + fr;
                bfv[n] = *reinterpret_cast<const bf16x8*>(&Bs[row * 64 + ((slot ^ (row & 7)) << 3)]);
            }
#pragma unroll
            for (int m = 0; m < 4; ++m)
#pragma unroll
                for (int n = 0; n < 4; ++n)
                    acc[m][n] = __builtin_amdgcn_mfma_f32_16x16x32_bf16(af[m], bfv[n], acc[m][n], 0, 0, 0);
        }
        __syncthreads();
    }

    int rb = m0 + wr * 64 + fh * 4;
    int cb = n0 + wc * 64 + fr;

    if constexpr (EPI == 3) {
        int mat = n0 >> 10;
        if (mat < 2) {
            // fused per-head rms_norm + rope for q (mat 0) / k (mat 1)
            unsigned short* outp = (mat == 0) ? Cb : Kb;
#pragma unroll
            for (int m = 0; m < 4; ++m) {
#pragma unroll
                for (int j = 0; j < 4; ++j) {
                    int gr = rb + m * 16 + j;
                    int s = gr & (SS - 1);
                    float ss = 0.0f;
#pragma unroll
                    for (int n = 0; n < 4; ++n) ss += acc[m][n][j] * acc[m][n][j];
                    ss += __shfl_xor(ss, 1, 64);
                    ss += __shfl_xor(ss, 2, 64);
                    ss += __shfl_xor(ss, 4, 64);
                    ss += __shfl_xor(ss, 8, 64);
                    float rsn = rsqrtf(ss * (1.0f / (float)HD) + 1e-6f);
                    float nv0 = acc[m][0][j] * rsn;
                    float nv1 = acc[m][1][j] * rsn;
                    float nv2 = acc[m][2][j] * rsn;
                    float nv3 = acc[m][3][j] * rsn;
                    float2 t0 = tab[s * 32 + fr];
                    float2 t1 = tab[s * 32 + fr + 16];
                    float o0 = nv0 * t0.x + nv2 * t0.y;
                    float o1 = nv1 * t1.x + nv3 * t1.y;
                    float o2 = nv2 * t0.x - nv0 * t0.y;
                    float o3 = nv3 * t1.x - nv1 * t1.y;
                    size_t rowo = (size_t)gr * DM + ((cb)&1023);
                    outp[rowo] = f2bfb(o0);
                    outp[rowo + 16] = f2bfb(o1);
                    outp[rowo + 32] = f2bfb(o2);
                    outp[rowo + 48] = f2bfb(o3);
                }
            }
        } else {
            // v path: copy (layer 0) or mix with v1
            float la = V1out ? 0.0f : *lambp;
#pragma unroll
            for (int n = 0; n < 4; ++n) {
                int gc = cb + n * 16;
#pragma unroll
                for (int m = 0; m < 4; ++m) {
#pragma unroll
                    for (int j = 0; j < 4; ++j) {
                        int gr = rb + m * 16 + j;
                        size_t o = (size_t)gr * DM + (gc & 1023);
                        unsigned short bv = f2bfb(acc[m][n][j]);
                        if (V1out) {
                            Vb[o] = bv;
                            V1out[o] = bv;
                        } else {
                            float mixed = (1.0f - la) * bfb2f(bv) + la * bfb2f(V1in[o]);
                            Vb[o] = f2bfb(mixed);
                        }
                    }
                }
            }
        }
        return;
    }

#pragma unroll
    for (int n = 0; n < 4; ++n) {
        int gc = cb + n * 16;
#pragma unroll
        for (int m = 0; m < 4; ++m) {
#pragma unroll
            for (int j = 0; j < 4; ++j) {
                int gr = rb + m * 16 + j;
                float val = acc[m][n][j];
                if constexpr (EPI == 0) {
                    Cb[(size_t)gr * ldC + gc] = f2bfb(val);
                } else if constexpr (EPI == 1) {
                    float rl = fmaxf(val, 0.0f);
                    Cb[(size_t)gr * ldC + gc] = f2bfb(rl * rl);
                } else if constexpr (EPI == 2) {
                    size_t o = (size_t)gr * ldC + gc;
                    Cf[o] = Cf[o] + val;
                }
            }
        }
    }
}

// ---------- lm_head GEMM (single-buffer), fused softcap+exp partial-sum ----------
// exp(softcap(z)-30) == exp(-60/(t+1)) with t = exp(z/15)   [exact identity]
__global__ __launch_bounds__(256) void gemm_lm(
    const unsigned short* __restrict__ A, const unsigned short* __restrict__ Bw,
    const int* __restrict__ target, float* __restrict__ part, float* __restrict__ zbf,
    int K)
{
    __shared__ unsigned short As[128 * 64];
    __shared__ unsigned short Bs[128 * 64];
    __shared__ float reds[2][2][64];

    // bijective xcd chunking: nwg = 4704 = 8 * 588
    int orig = blockIdx.x;
    int xcd = orig & 7, rank = orig >> 3;
    int e = xcd * 588 + rank;
    int g = 0;
#pragma unroll
    for (int it = 0; it < 7; ++it) {
        int sz = (g & 1) ? 584 : 592;
        if (e >= sz) { e -= sz; ++g; }
    }
    int nj = g & 1, mi = g >> 1;
    int bxl = e >> 3, byl = e & 7;
    int bx = nj * 74 + bxl;
    int by = mi * 8 + byl;
    int m0 = by * 128, n0 = bx * 128;

    int tid = threadIdx.x, lane = tid & 63, w = tid >> 6;
    int wr = w >> 1, wc = w & 1;
    int rsub = lane >> 3, sl = lane & 7;
    int ssrc = sl ^ rsub;
    int fr = lane & 15, fh = lane >> 4;

    size_t arow[4], brow[4];
#pragma unroll
    for (int i = 0; i < 4; ++i) {
        int c = 4 * w + i;
        arow[i] = (size_t)(m0 + 8 * c + rsub) * K + ssrc * 8;
        brow[i] = (size_t)(n0 + 8 * c + rsub) * K + ssrc * 8;
    }

    f32x4 acc[4][4];
#pragma unroll
    for (int m = 0; m < 4; ++m)
#pragma unroll
        for (int n = 0; n < 4; ++n) acc[m][n] = 0.0f;

    int NT = K >> 6;
    for (int kt = 0; kt < NT; ++kt) {
        int kb = kt * 64;
#pragma unroll
        for (int i = 0; i < 4; ++i) {
            __builtin_amdgcn_global_load_lds((gas_t)(const void*)(A + arow[i] + kb),
                                             (las_t)(void*)(&As[(4 * w + i) * 512]), 16, 0, 0);
            __builtin_amdgcn_global_load_lds((gas_t)(const void*)(Bw + brow[i] + kb),
                                             (las_t)(void*)(&Bs[(4 * w + i) * 512]), 16, 0, 0);
        }
        __syncthreads();
#pragma unroll
        for (int kk = 0; kk < 2; ++kk) {
            int slot = kk * 4 + fh;
            bf16x8 af[4], bfv[4];
#pragma unroll
            for (int m = 0; m < 4; ++m) {
                int row = wr * 64 + m * 16 + fr;
                af[m] = *reinterpret_cast<const bf16x8*>(&As[row * 64 + ((slot ^ (row & 7)) << 3)]);
            }
#pragma unroll
            for (int n = 0; n < 4; ++n) {
                int row = wc * 64 + n * 16 + fr;
                bfv[n] = *reinterpret_cast<const bf16x8*>(&Bs[row * 64 + ((slot ^ (row & 7)) << 3)]);
            }
#pragma unroll
            for (int m = 0; m < 4; ++m)
#pragma unroll
                for (int n = 0; n < 4; ++n)
                    acc[m][n] = __builtin_amdgcn_mfma_f32_16x16x32_bf16(af[m], bfv[n], acc[m][n], 0, 0, 0);
        }
        __syncthreads();
    }

    int rb = m0 + wr * 64 + fh * 4;
    int cb = n0 + wc * 64 + fr;
#pragma unroll
    for (int m = 0; m < 4; ++m) {
#pragma unroll
        for (int j = 0; j < 4; ++j) {
            int gr = rb + m * 16 + j;
            int tg = target[gr];
            float rs = 0.0f;
#pragma unroll
            for (int n = 0; n < 4; ++n) {
                int gc = cb + n * 16;
                if (gc < VV) {
                    float zv = acc[m][n][j];
                    float tt = __expf(zv * 0.066666667f);     // exp(z/15)
                    rs += __expf(__fdividef(-60.0f, tt + 1.0f));
                    if (gc == tg) zbf[gr] = 30.0f - 60.0f / (tt + 1.0f);
                }
            }
            rs += __shfl_xor(rs, 1, 64);
            rs += __shfl_xor(rs, 2, 64);
            rs += __shfl_xor(rs, 4, 64);
            rs += __shfl_xor(rs, 8, 64);
            if (fr == 0) reds[wr][wc][m * 16 + fh * 4 + j] = rs;
        }
    }
    __syncthreads();
    if (tid < 128) {
        int wrx = tid >> 6, r64 = tid & 63;
        part[(size_t)(m0 + tid) * NXLM + bx] = reds[wrx][0][r64] + reds[wrx][1][r64];
    }
}

// merge NXLM partial sums per token -> loss = 30 + log(sum) - z_target
__global__ __launch_bounds__(256) void loss_merge_kernel(
    const float* __restrict__ part, const float* __restrict__ zbf,
    const int* __restrict__ target, float* __restrict__ out)
{
    int t = blockIdx.x;
    float l = 0.0f;
    for (int i = threadIdx.x; i < NXLM; i += 256) l += part[(size_t)t * NXLM + i];
    l = block_sum256(l);
    if (threadIdx.x == 0) {
        int tg = target[t];
        float lse = 30.0f + logf(l);
        bool masked = (tg == 16384) || (tg == 18433) || (tg == 18690);
        out[t] = masked ? 0.0f : (lse - zbf[t]);
    }
}

// ---------- BM=64 variant (wo, w1, w2); optional split-K with bf16 partial stores ----------
// EPI 0: bf16. EPI 1: relu^2 bf16. EPI 2: fp32 +=. EPI 4: bf16 partial store at ks*TT*DM.
template <int EPI, int KS = 1>
__global__ __launch_bounds__(256) void gemm_bb64(
    const unsigned short* __restrict__ A, const unsigned short* __restrict__ Bw,
    unsigned short* __restrict__ Cb, float* __restrict__ Cf,
    int NX, int K, int ldC)
{
    __shared__ unsigned short As[64 * 64];
    __shared__ unsigned short Bs[128 * 64];

    int nwg = gridDim.x;
    int orig = blockIdx.x;
    int qq = nwg >> 3, rr = nwg & 7;
    int xcd = orig & 7, rem = orig >> 3;
    int wg = (xcd < rr ? xcd * (qq + 1) : rr * (qq + 1) + (xcd - rr) * qq) + rem;
    int per = nwg / KS;
    int ks = (KS == 1) ? 0 : (wg / per);
    int rem2 = (KS == 1) ? wg : (wg % per);
    int bx = rem2 % NX, by = rem2 / NX;
    int m0 = by * 64, n0 = bx * 128;
    int KSUB = K / KS;
    int kbase = ks * KSUB;

    int tid = threadIdx.x, lane = tid & 63, w = tid >> 6;
    int wr = w >> 1, wc = w & 1;
    int rsub = lane >> 3, sl = lane & 7;
    int ssrc = sl ^ rsub;
    int fr = lane & 15, fh = lane >> 4;

    size_t arow[2], brow[4];
#pragma unroll
    for (int i = 0; i < 2; ++i) {
        int c = 2 * w + i;
        arow[i] = (size_t)(m0 + 8 * c + rsub) * K + ssrc * 8;
    }
#pragma unroll
    for (int i = 0; i < 4; ++i) {
        int c = 4 * w + i;
        brow[i] = (size_t)(n0 + 8 * c + rsub) * K + ssrc * 8;
    }

    f32x4 acc[2][4];
#pragma unroll
    for (int m = 0; m < 2; ++m)
#pragma unroll
        for (int n = 0; n < 4; ++n) acc[m][n] = 0.0f;

    int NT = KSUB >> 6;
    for (int kt = 0; kt < NT; ++kt) {
        int kb = kbase + kt * 64;
#pragma unroll
        for (int i = 0; i < 2; ++i)
            __builtin_amdgcn_global_load_lds((gas_t)(const void*)(A + arow[i] + kb),
                                             (las_t)(void*)(&As[(2 * w + i) * 512]), 16, 0, 0);
#pragma unroll
        for (int i = 0; i < 4; ++i)
            __builtin_amdgcn_global_load_lds((gas_t)(const void*)(Bw + brow[i] + kb),
                                             (las_t)(void*)(&Bs[(4 * w + i) * 512]), 16, 0, 0);
        __syncthreads();
#pragma unroll
        for (int kk = 0; kk < 2; ++kk) {
            int slot = kk * 4 + fh;
            bf16x8 af[2], bfv[4];
#pragma unroll
            for (int m = 0; m < 2; ++m) {
                int row = wr * 32 + m * 16 + fr;
                af[m] = *reinterpret_cast<const bf16x8*>(&As[row * 64 + ((slot ^ (row & 7)) << 3)]);
            }
#pragma unroll
            for (int n = 0; n < 4; ++n) {
                int row = wc * 64 + n * 16 + fr;
                bfv[n] = *reinterpret_cast<const bf16x8*>(&Bs[row * 64 + ((slot ^ (row & 7)) << 3)]);
            }
#pragma unroll
            for (int m = 0; m < 2; ++m)
#pragma unroll
                for (int n = 0; n < 4; ++n)
                    acc[m][n] = __builtin_amdgcn_mfma_f32_16x16x32_bf16(af[m], bfv[n], acc[m][n], 0, 0, 0);
        }
        __syncthreads();
    }

    int rb = m0 + wr * 32 + fh * 4;
    int cb = n0 + wc * 64 + fr;
#pragma unroll
    for (int n = 0; n < 4; ++n) {
        int gc = cb + n * 16;
#pragma unroll
        for (int m = 0; m < 2; ++m) {
#pragma unroll
            for (int j = 0; j < 4; ++j) {
                int gr = rb + m * 16 + j;
                float val = acc[m][n][j];
                if constexpr (EPI == 0) {
                    Cb[(size_t)gr * ldC + gc] = f2bfb(val);
                } else if constexpr (EPI == 1) {
                    float rl = fmaxf(val, 0.0f);
                    Cb[(size_t)gr * ldC + gc] = f2bfb(rl * rl);
                } else if constexpr (EPI == 2) {
                    size_t o = (size_t)gr * ldC + gc;
                    Cf[o] = Cf[o] + val;
                } else {
                    Cb[(size_t)ks * ((size_t)TT * DM) + (size_t)gr * ldC + gc] = f2bfb(val);
                }
            }
        }
    }
}

// MFMA flash attention, mask-sparse: local sliding-window pass + packed level>0 pass.
__global__ __launch_bounds__(256) void attn_mfma_kernel(
    const unsigned short* __restrict__ q, const unsigned short* __restrict__ k,
    const unsigned short* __restrict__ v,
    const unsigned short* __restrict__ kp, const unsigned short* __restrict__ vp,
    const int* __restrict__ gpos, const int* __restrict__ nbuf,
    unsigned short* __restrict__ y)
{
    __shared__ unsigned short Qs[64][APITCH];
    __shared__ unsigned short Ks[64][APITCH];
    __shared__ unsigned short Vt[64][APITCH];
    __shared__ unsigned short Ps[64][APITCH];
    __shared__ int posS[64];

    int bh = blockIdx.x;
    int b = bh >> 4, h = bh & 15;
    int q0 = blockIdx.y * 64;
    size_t base = (size_t)b * SS * DM + h * HD;
    int tid = threadIdx.x;
    int lane = tid & 63, w = tid >> 6;
    int srow = tid >> 2, sc = tid & 3;

    {
        const unsigned short* src = q + base + (size_t)(q0 + srow) * DM;
        *reinterpret_cast<uint4*>(&Qs[srow][sc * 8]) = *reinterpret_cast<const uint4*>(src + sc * 8);
        *reinterpret_cast<uint4*>(&Qs[srow][(sc + 4) * 8]) = *reinterpret_cast<const uint4*>(src + (sc + 4) * 8);
    }
    __syncthreads();

    int fr = lane & 15, fc = (lane >> 4) * 8;
    int rj = (lane >> 4) * 4;

    bf16x8 qa[2];
    qa[0] = *reinterpret_cast<const bf16x8*>(&Qs[w * 16 + fr][fc]);
    qa[1] = *reinterpret_cast<const bf16x8*>(&Qs[w * 16 + fr][32 + fc]);

    float mreg[4], lreg[4];
    f32x4 yacc[4];
#pragma unroll
    for (int j = 0; j < 4; ++j) { mreg[j] = -1e30f; lreg[j] = 0.0f; yacc[j] = 0.0f; }

    int nbp = nbuf[BBATCH + b];

    int t0 = (q0 >= 256) ? ((q0 - 256) >> 6) : 0;
    int t1 = q0 >> 6;
    for (int pass = 0; pass < 2; ++pass) {
        int kt_begin = (pass == 0) ? t0 : 0;
        int kt_end = (pass == 0) ? (t1 + 1) : (nbp >> 6);
        for (int kt = kt_begin; kt < kt_end; ++kt) {
            int k0 = kt * 64;
            if (pass == 1) {
                if (gpos[b * SS + k0] > q0 - 194) break;
            }
            __syncthreads();
            {
                const unsigned short* ksrc = (pass == 0) ? (k + base) : (kp + base);
                const unsigned short* vsrc = (pass == 0) ? (v + base) : (vp + base);
                size_t goff = (size_t)(k0 + srow) * DM;
                uint4 kv0 = *reinterpret_cast<const uint4*>(ksrc + goff + sc * 8);
                uint4 kv1 = *reinterpret_cast<const uint4*>(ksrc + goff + (sc + 4) * 8);
                *reinterpret_cast<uint4*>(&Ks[srow][sc * 8]) = kv0;
                *reinterpret_cast<uint4*>(&Ks[srow][(sc + 4) * 8]) = kv1;
                uint4 vv0 = *reinterpret_cast<const uint4*>(vsrc + goff + sc * 8);
                uint4 vv1 = *reinterpret_cast<const uint4*>(vsrc + goff + (sc + 4) * 8);
                const unsigned short* e0 = reinterpret_cast<const unsigned short*>(&vv0);
                const unsigned short* e1 = reinterpret_cast<const unsigned short*>(&vv1);
#pragma unroll
                for (int i = 0; i < 8; ++i) Vt[sc * 8 + i][srow] = e0[i];
#pragma unroll
                for (int i = 0; i < 8; ++i) Vt[(sc + 4) * 8 + i][srow] = e1[i];
                if (pass == 1 && tid < 64) posS[tid] = gpos[b * SS + k0 + tid];
            }
            __syncthreads();

            f32x4 sacc[4];
#pragma unroll
            for (int n = 0; n < 4; ++n) {
                bf16x8 kb0 = *reinterpret_cast<const bf16x8*>(&Ks[n * 16 + fr][fc]);
                bf16x8 kb1 = *reinterpret_cast<const bf16x8*>(&Ks[n * 16 + fr][32 + fc]);
                f32x4 a = {0.0f, 0.0f, 0.0f, 0.0f};
                a = __builtin_amdgcn_mfma_f32_16x16x32_bf16(qa[0], kb0, a, 0, 0, 0);
                a = __builtin_amdgcn_mfma_f32_16x16x32_bf16(qa[1], kb1, a, 0, 0, 0);
                sacc[n] = a;
            }

            float sm[4][4];
            float cm[4] = {-1e30f, -1e30f, -1e30f, -1e30f};
#pragma unroll
            for (int n = 0; n < 4; ++n) {
                int kg = (pass == 0) ? (k0 + n * 16 + fr) : posS[n * 16 + fr];
#pragma unroll
                for (int j = 0; j < 4; ++j) {
                    int qg = q0 + w * 16 + rj + j;
                    bool valid = (pass == 0) ? ((kg <= qg) && (qg - kg <= 256))
                                             : (kg < qg - 256);
                    float s = valid ? sacc[n][j] * 0.125f : -1e30f;
                    sm[n][j] = s;
                    cm[j] = fmaxf(cm[j], s);
                }
            }
#pragma unroll
            for (int j = 0; j < 4; ++j) {
                cm[j] = fmaxf(cm[j], __shfl_xor(cm[j], 1, 64));
                cm[j] = fmaxf(cm[j], __shfl_xor(cm[j], 2, 64));
                cm[j] = fmaxf(cm[j], __shfl_xor(cm[j], 4, 64));
                cm[j] = fmaxf(cm[j], __shfl_xor(cm[j], 8, 64));
            }
            float sj[4], ps[4];
#pragma unroll
            for (int j = 0; j < 4; ++j) {
                float nm = fmaxf(mreg[j], cm[j]);
                sj[j] = __expf(mreg[j] - nm);
                mreg[j] = nm;
                ps[j] = 0.0f;
            }
#pragma unroll
            for (int n = 0; n < 4; ++n) {
#pragma unroll
                for (int j = 0; j < 4; ++j) {
                    float p = (sm[n][j] > -1e29f) ? __expf(sm[n][j] - mreg[j]) : 0.0f;
                    Ps[w * 16 + rj + j][n * 16 + fr] = f2bfb(p);
                    ps[j] += p;
                }
            }
#pragma unroll
            for (int j = 0; j < 4; ++j) {
                float t = ps[j];
                t += __shfl_xor(t, 1, 64); t += __shfl_xor(t, 2, 64);
                t += __shfl_xor(t, 4, 64); t += __shfl_xor(t, 8, 64);
                lreg[j] = lreg[j] * sj[j] + t;
            }
#pragma unroll
            for (int n = 0; n < 4; ++n)
#pragma unroll
                for (int j = 0; j < 4; ++j) yacc[n][j] *= sj[j];

            bf16x8 pa0 = *reinterpret_cast<const bf16x8*>(&Ps[w * 16 + fr][fc]);
            bf16x8 pa1 = *reinterpret_cast<const bf16x8*>(&Ps[w * 16 + fr][32 + fc]);
#pragma unroll
            for (int n = 0; n < 4; ++n) {
                bf16x8 vb0 = *reinterpret_cast<const bf16x8*>(&Vt[n * 16 + fr][fc]);
                bf16x8 vb1 = *reinterpret_cast<const bf16x8*>(&Vt[n * 16 + fr][32 + fc]);
                yacc[n] = __builtin_amdgcn_mfma_f32_16x16x32_bf16(pa0, vb0, yacc[n], 0, 0, 0);
                yacc[n] = __builtin_amdgcn_mfma_f32_16x16x32_bf16(pa1, vb1, yacc[n], 0, 0, 0);
            }
        }
    }

    float inv[4];
#pragma unroll
    for (int j = 0; j < 4; ++j) inv[j] = 1.0f / lreg[j];
#pragma unroll
    for (int n = 0; n < 4; ++n) {
#pragma unroll
        for (int j = 0; j < 4; ++j) {
            int qg = q0 + w * 16 + rj + j;
            y[base + (size_t)qg * DM + n * 16 + fr] = f2bfb(yacc[n][j] * inv[j]);
        }
    }
}

extern "C" void kernel_launch(void* const* d_in, const int* in_sizes, int n_in,
                              void* d_out, int out_size, void* d_ws, size_t ws_size,
                              hipStream_t stream)
{
    const int* idx = (const int*)d_in[0];
    const int* target = (const int*)d_in[1];
    const float* wte = (const float*)d_in[2];
    const float* lambdas = (const float*)d_in[3];
    const float* lamb = (const float*)d_in[4];
    const float* wq = (const float*)d_in[5];
    const float* wk = (const float*)d_in[6];
    const float* wv = (const float*)d_in[7];
    const float* wo = (const float*)d_in[8];
    const float* w1 = (const float*)d_in[9];
    const float* w2 = (const float*)d_in[10];
    const float* lm_head = (const float*)d_in[11];
    float* out = (float*)d_out;

    char* ws = (char*)d_ws;
    const size_t MB = (size_t)1 << 20;
    float* x            = (float*)(ws);
    unsigned short* x0  = (unsigned short*)(ws + 16 * MB);
    unsigned short* nrm = (unsigned short*)(ws + 24 * MB);
    unsigned short* qb  = (unsigned short*)(ws + 32 * MB);
    unsigned short* kb  = (unsigned short*)(ws + 40 * MB);
    unsigned short* vb  = (unsigned short*)(ws + 48 * MB);
    unsigned short* v1b = (unsigned short*)(ws + 56 * MB);
    unsigned short* yb  = (unsigned short*)(ws + 64 * MB);
    unsigned short* hid = (unsigned short*)(ws + 72 * MB);   // 32 MB; dead during attention & lm
    unsigned short* kp  = (unsigned short*)(ws + 72 * MB);   // packed K (8 MB), overlaps hid
    unsigned short* vp  = (unsigned short*)(ws + 80 * MB);   // packed V (8 MB), overlaps hid
    float* part         = (float*)(ws + 72 * MB);            // lm partials (2.4 MB), lm-time only
    float* zbf          = (float*)(ws + 78 * MB);            // lm target logit (16 KB), lm-time only
    unsigned short* w2p = qb;                                 // w2 split-K partials (2x8 MB = qb+kb, dead then)
    int* levels         = (int*)(ws + 104 * MB);
    int* gpos           = (int*)(ws + 104 * MB + 64 * 1024);
    int* nbuf           = (int*)(ws + 104 * MB + 128 * 1024);
    float2* ropetab     = (float2*)(ws + 104 * MB + 256 * 1024); // 512 KB, persistent
    unsigned short* wqkvb = (unsigned short*)(ws + 105 * MB); // [NL][3][1024][1024]
    unsigned short* wob = (unsigned short*)(ws + 129 * MB);
    unsigned short* w1b = (unsigned short*)(ws + 137 * MB);
    unsigned short* w2b = (unsigned short*)(ws + 169 * MB);
    unsigned short* lmb = (unsigned short*)(ws + 201 * MB);
    bool cvt = ws_size >= 238 * MB;

    if (cvt) {
        int n1 = DM * DM;
        int nff = NL * FFD * DM;
        for (int i = 0; i < NL; ++i) {
            cvtw_kernel<<<n1 / 1024, 256, 0, stream>>>(wq + (size_t)i * n1, wqkvb + ((size_t)i * 3 + 0) * n1, n1);
            cvtw_kernel<<<n1 / 1024, 256, 0, stream>>>(wk + (size_t)i * n1, wqkvb + ((size_t)i * 3 + 1) * n1, n1);
            cvtw_kernel<<<n1 / 1024, 256, 0, stream>>>(wv + (size_t)i * n1, wqkvb + ((size_t)i * 3 + 2) * n1, n1);
        }
        cvtw_kernel<<<NL * n1 / 1024, 256, 0, stream>>>(wo, wob, NL * n1);
        cvtw_kernel<<<nff / 1024, 256, 0, stream>>>(w1, w1b, nff);
        cvtw_kernel<<<nff / 1024, 256, 0, stream>>>(w2, w2b, nff);
        cvtpad_kernel<<<(VP * DM) / 1024, 256, 0, stream>>>(lm_head, lmb, VV * DM, VP * DM);
    }
    ropetab_kernel<<<SS / 8, 256, 0, stream>>>(ropetab);

    embed_kernel<<<TT, 256, 0, stream>>>(idx, wte, x, x0, levels);
    pack_kernel<<<BBATCH, 256, 0, stream>>>(levels, gpos, nbuf);
    mixnorm_kernel<<<TT, 256, 0, stream>>>(x, x0, lambdas, nrm);

    for (int i = 0; i < NL; ++i) {
        if (cvt) {
            if (i == 0)
                gemm_bb<3><<<768, 256, 0, stream>>>(nrm, wqkvb + (size_t)i * 3 * DM * DM,
                                                    qb, nullptr, kb, vb, nullptr, v1b, nullptr, ropetab, 24, DM, DM);
            else
                gemm_bb<3><<<768, 256, 0, stream>>>(nrm, wqkvb + (size_t)i * 3 * DM * DM,
                                                    qb, nullptr, kb, vb, v1b, nullptr, lamb + i, ropetab, 24, DM, DM);
        }
        gather_kernel<<<BBATCH * SS / 4, 256, 0, stream>>>(kb, vb, gpos, nbuf, kp, vp);
        attn_mfma_kernel<<<dim3(BBATCH * NH, SS / 64), 256, 0, stream>>>(qb, kb, vb, kp, vp, gpos, nbuf, yb);
        if (cvt) {
            gemm_bb64<2><<<512, 256, 0, stream>>>(yb, wob + (size_t)i * DM * DM, nullptr, x, 8, DM, DM);
            norm_kernel<<<TT, 256, 0, stream>>>(x, nrm);
            gemm_bb64<1><<<2048, 256, 0, stream>>>(nrm, w1b + (size_t)i * FFD * DM, hid, nullptr, 32, DM, FFD);
            gemm_bb64<4, 2><<<1024, 256, 0, stream>>>(hid, w2b + (size_t)i * DM * FFD, w2p, nullptr, 8, FFD, DM);
            if (i < NL - 1)
                w2mix_kernel<<<TT, 256, 0, stream>>>(x, w2p, w2p + (size_t)TT * DM, x0,
                                                     lambdas + 2 * (i + 1), nrm, 1);
            else
                w2mix_kernel<<<TT, 256, 0, stream>>>(x, w2p, w2p + (size_t)TT * DM, x0,
                                                     nullptr, nrm, 0);
        }
    }

    gemm_lm<<<NXLM * 32, 256, 0, stream>>>(nrm, lmb, target, part, zbf, DM);
    loss_merge_kernel<<<TT, 256, 0, stream>>>(part, zbf, target, out);
}

// Round 18
// 1251.797 us; speedup vs baseline: 1.1751x; 1.0429x over previous
//
#include <hip/hip_runtime.h>
#include <hip/hip_bf16.h>

#define TT 4096
#define SS 2048
#define BBATCH 2
#define DM 1024
#define NH 16
#define HD 64
#define FFD 4096
#define NL 4
#define VV 18691
#define VP 18816
#define APITCH 72
#define NXLM 147
#define SENT 0x3FFFFFFF

typedef __bf16 bf16x8 __attribute__((ext_vector_type(8)));
typedef float f32x4 __attribute__((ext_vector_type(4)));
typedef const __attribute__((address_space(1))) void* gas_t;
typedef __attribute__((address_space(3))) void* las_t;

__device__ __forceinline__ float bfb2f(unsigned short u) {
    union { unsigned int i; float f; } x;
    x.i = ((unsigned int)u) << 16;
    return x.f;
}
__device__ __forceinline__ unsigned short f2bfb(float f) {
    union { float f; unsigned int i; } x;
    x.f = f;
    unsigned int r = 0x7fffu + ((x.i >> 16) & 1u);
    x.i += r;
    return (unsigned short)(x.i >> 16);
}

__device__ __forceinline__ float wave_sum(float v) {
#pragma unroll
    for (int o = 32; o; o >>= 1) v += __shfl_xor(v, o, 64);
    return v;
}

__device__ __forceinline__ float block_sum256(float v) {
    __shared__ float sb[4];
    v = wave_sum(v);
    int wid = threadIdx.x >> 6;
    if ((threadIdx.x & 63) == 0) sb[wid] = v;
    __syncthreads();
    float t = sb[0] + sb[1] + sb[2] + sb[3];
    __syncthreads();
    return t;
}

// ---- weight fp32 -> bf16 conversion ----
__global__ __launch_bounds__(256) void cvtw_kernel(const float* __restrict__ src,
                                                   unsigned short* __restrict__ dst, int n)
{
    int i = (blockIdx.x * 256 + threadIdx.x) * 4;
    if (i >= n) return;
    float4 f = *reinterpret_cast<const float4*>(src + i);
    ushort4 u;
    u.x = f2bfb(f.x); u.y = f2bfb(f.y); u.z = f2bfb(f.z); u.w = f2bfb(f.w);
    *reinterpret_cast<ushort4*>(dst + i) = u;
}

__global__ __launch_bounds__(256) void cvtpad_kernel(const float* __restrict__ src,
                                                     unsigned short* __restrict__ dst,
                                                     int nreal, int ntot)
{
    int i = (blockIdx.x * 256 + threadIdx.x) * 4;
    if (i >= ntot) return;
    ushort4 u = {0, 0, 0, 0};
    if (i < nreal) {
        float4 f = *reinterpret_cast<const float4*>(src + i);
        u.x = f2bfb(f.x); u.y = f2bfb(f.y); u.z = f2bfb(f.z); u.w = f2bfb(f.w);
    }
    *reinterpret_cast<ushort4*>(dst + i) = u;
}

// rope cos/sin table: tab[s][j] = (cos, sin)(s * 10000^(-j/32))
__global__ __launch_bounds__(256) void ropetab_kernel(float2* __restrict__ tab)
{
    int s = blockIdx.x * 8 + (threadIdx.x >> 5);
    int j = threadIdx.x & 31;
    float invf = exp2f(-(float)j * 0.41524101186092025f);
    float ang = (float)s * invf;
    float sn, cs;
    sincosf(ang, &sn, &cs);
    tab[s * 32 + j] = make_float2(cs, sn);
}

// x = rms_norm(wte[idx]); x0 = bf16(x); levels[t]
__global__ __launch_bounds__(256) void embed_kernel(
    const int* __restrict__ idx, const float* __restrict__ wte,
    float* __restrict__ x, unsigned short* __restrict__ x0, int* __restrict__ levels)
{
    int t = blockIdx.x;
    int id = idx[t];
    const float* row = wte + (size_t)id * DM;
    float4 v = *reinterpret_cast<const float4*>(row + threadIdx.x * 4);
    float ss = v.x * v.x + v.y * v.y + v.z * v.z + v.w * v.w;
    float tot = block_sum256(ss);
    float rs = rsqrtf(tot / (float)DM + 1e-6f);
    float4 o;
    o.x = v.x * rs; o.y = v.y * rs; o.z = v.z * rs; o.w = v.w * rs;
    size_t off = (size_t)t * DM + threadIdx.x * 4;
    *reinterpret_cast<float4*>(x + off) = o;
    ushort4 ub;
    ub.x = f2bfb(o.x); ub.y = f2bfb(o.y); ub.z = f2bfb(o.z); ub.w = f2bfb(o.w);
    *reinterpret_cast<ushort4*>(x0 + off) = ub;
    if (threadIdx.x == 0) levels[t] = (id >= 16385) + (id >= 18434);
}

// per-batch ascending list of positions with level>0
__global__ __launch_bounds__(256) void pack_kernel(
    const int* __restrict__ levels, int* __restrict__ gpos, int* __restrict__ nbuf)
{
    int b = blockIdx.x;
    const int* lv = levels + b * SS;
    int* gp = gpos + b * SS;
    __shared__ int wsum[4];
    __shared__ int base;
    if (threadIdx.x == 0) base = 0;
    __syncthreads();
    int lane = threadIdx.x & 63, w = threadIdx.x >> 6;
    for (int c = 0; c < SS; c += 256) {
        int s = c + threadIdx.x;
        int flag = (lv[s] > 0) ? 1 : 0;
        unsigned long long mask = __ballot(flag);
        int pre = __popcll(mask & ((1ull << lane) - 1ull));
        int wtot = __popcll(mask);
        if (lane == 0) wsum[w] = wtot;
        __syncthreads();
        int woff = 0;
#pragma unroll
        for (int i = 0; i < 4; ++i) if (i < w) woff += wsum[i];
        int tot = wsum[0] + wsum[1] + wsum[2] + wsum[3];
        int mybase = base;
        if (flag) gp[mybase + woff + pre] = s;
        __syncthreads();
        if (threadIdx.x == 0) base += tot;
        __syncthreads();
    }
    int nb = base;
    int nbp = (nb + 63) & ~63;
    for (int i = nb + threadIdx.x; i < SS; i += 256) gp[i] = SENT;
    if (threadIdx.x == 0) { nbuf[b] = nb; nbuf[BBATCH + b] = nbp; }
}

// gather roped K and mixed V rows of level>0 positions into packed buffers (4 rows/block)
__global__ __launch_bounds__(256) void gather_kernel(
    const unsigned short* __restrict__ kb, const unsigned short* __restrict__ vb,
    const int* __restrict__ gpos, const int* __restrict__ nbuf,
    unsigned short* __restrict__ kp, unsigned short* __restrict__ vp)
{
    int gid = blockIdx.x * 4 + (threadIdx.x >> 6);
    int b = gid >> 11;
    int j = gid & (SS - 1);
    if (j >= nbuf[BBATCH + b]) return;
    int pos = gpos[b * SS + j];
    int lane = threadIdx.x & 63;
    size_t dst = ((size_t)b * SS + j) * DM + lane * 16;
    if (pos < SS) {
        size_t src = ((size_t)b * SS + pos) * DM + lane * 16;
        *reinterpret_cast<uint4*>(kp + dst) = *reinterpret_cast<const uint4*>(kb + src);
        *reinterpret_cast<uint4*>(kp + dst + 8) = *reinterpret_cast<const uint4*>(kb + src + 8);
        *reinterpret_cast<uint4*>(vp + dst) = *reinterpret_cast<const uint4*>(vb + src);
        *reinterpret_cast<uint4*>(vp + dst + 8) = *reinterpret_cast<const uint4*>(vb + src + 8);
    } else {
        uint4 z = {0, 0, 0, 0};
        *reinterpret_cast<uint4*>(kp + dst) = z;
        *reinterpret_cast<uint4*>(kp + dst + 8) = z;
        *reinterpret_cast<uint4*>(vp + dst) = z;
        *reinterpret_cast<uint4*>(vp + dst + 8) = z;
    }
}

// xr = l0*x + l1*x0 (written back to x); out = bf16(rms_norm(xr))
__global__ __launch_bounds__(256) void mixnorm_kernel(
    float* __restrict__ x, const unsigned short* __restrict__ x0,
    const float* __restrict__ lam2, unsigned short* __restrict__ out)
{
    int t = blockIdx.x;
    size_t off = (size_t)t * DM + threadIdx.x * 4;
    float4 xv = *reinterpret_cast<const float4*>(x + off);
    float l0 = lam2[0], l1 = lam2[1];
    ushort4 u = *reinterpret_cast<const ushort4*>(x0 + off);
    float4 r;
    r.x = l0 * xv.x + l1 * bfb2f(u.x);
    r.y = l0 * xv.y + l1 * bfb2f(u.y);
    r.z = l0 * xv.z + l1 * bfb2f(u.z);
    r.w = l0 * xv.w + l1 * bfb2f(u.w);
    float ss = r.x * r.x + r.y * r.y + r.z * r.z + r.w * r.w;
    float tot = block_sum256(ss);
    float rs = rsqrtf(tot / (float)DM + 1e-6f);
    *reinterpret_cast<float4*>(x + off) = r;
    ushort4 ob;
    ob.x = f2bfb(r.x * rs); ob.y = f2bfb(r.y * rs);
    ob.z = f2bfb(r.z * rs); ob.w = f2bfb(r.w * rs);
    *reinterpret_cast<ushort4*>(out + off) = ob;
}

// out = bf16(rms_norm(x)), x unmodified
__global__ __launch_bounds__(256) void norm_kernel(
    const float* __restrict__ x, unsigned short* __restrict__ out)
{
    int t = blockIdx.x;
    size_t off = (size_t)t * DM + threadIdx.x * 4;
    float4 r = *reinterpret_cast<const float4*>(x + off);
    float ss = r.x * r.x + r.y * r.y + r.z * r.z + r.w * r.w;
    float tot = block_sum256(ss);
    float rs = rsqrtf(tot / (float)DM + 1e-6f);
    ushort4 ob;
    ob.x = f2bfb(r.x * rs); ob.y = f2bfb(r.y * rs);
    ob.z = f2bfb(r.z * rs); ob.w = f2bfb(r.w * rs);
    *reinterpret_cast<ushort4*>(out + off) = ob;
}

// x += p0+p1 (bf16 partials); then mix with x0 (if domix) ; out = bf16(rms_norm)
__global__ __launch_bounds__(256) void w2mix_kernel(
    float* __restrict__ x, const unsigned short* __restrict__ p0,
    const unsigned short* __restrict__ p1, const unsigned short* __restrict__ x0,
    const float* __restrict__ lam2, unsigned short* __restrict__ out, int domix)
{
    int t = blockIdx.x;
    size_t off = (size_t)t * DM + threadIdx.x * 4;
    float4 xv = *reinterpret_cast<const float4*>(x + off);
    ushort4 a = *reinterpret_cast<const ushort4*>(p0 + off);
    ushort4 b = *reinterpret_cast<const ushort4*>(p1 + off);
    float4 r;
    r.x = xv.x + bfb2f(a.x) + bfb2f(b.x);
    r.y = xv.y + bfb2f(a.y) + bfb2f(b.y);
    r.z = xv.z + bfb2f(a.z) + bfb2f(b.z);
    r.w = xv.w + bfb2f(a.w) + bfb2f(b.w);
    if (domix) {
        float l0 = lam2[0], l1 = lam2[1];
        ushort4 u = *reinterpret_cast<const ushort4*>(x0 + off);
        r.x = l0 * r.x + l1 * bfb2f(u.x);
        r.y = l0 * r.y + l1 * bfb2f(u.y);
        r.z = l0 * r.z + l1 * bfb2f(u.z);
        r.w = l0 * r.w + l1 * bfb2f(u.w);
        *reinterpret_cast<float4*>(x + off) = r;
    }
    float ss = r.x * r.x + r.y * r.y + r.z * r.z + r.w * r.w;
    float tot = block_sum256(ss);
    float rs = rsqrtf(tot / (float)DM + 1e-6f);
    ushort4 ob;
    ob.x = f2bfb(r.x * rs); ob.y = f2bfb(r.y * rs);
    ob.z = f2bfb(r.z * rs); ob.w = f2bfb(r.w * rs);
    *reinterpret_cast<ushort4*>(out + off) = ob;
}

// ---------- fused QKV GEMM on BM=64 tile: q/k head-rmsnorm+rope, v copy/mix ----------
// N = 3072 (NX = 24), grid 1536. Wave owns 32 rows x 64 cols (one head per wc half).
__global__ __launch_bounds__(256) void gemm_qkv64(
    const unsigned short* __restrict__ A, const unsigned short* __restrict__ Bw,
    unsigned short* __restrict__ Qb, unsigned short* __restrict__ Kb,
    unsigned short* __restrict__ Vb,
    const unsigned short* __restrict__ V1in, unsigned short* __restrict__ V1out,
    const float* __restrict__ lambp, const float2* __restrict__ tab,
    int K)
{
    __shared__ unsigned short As[64 * 64];
    __shared__ unsigned short Bs[128 * 64];

    const int NX = 24;
    int nwg = gridDim.x;
    int orig = blockIdx.x;
    int qq = nwg >> 3, rr = nwg & 7;
    int xcd = orig & 7, rem = orig >> 3;
    int wg = (xcd < rr ? xcd * (qq + 1) : rr * (qq + 1) + (xcd - rr) * qq) + rem;
    int bx = wg % NX, by = wg / NX;
    int m0 = by * 64, n0 = bx * 128;

    int tid = threadIdx.x, lane = tid & 63, w = tid >> 6;
    int wr = w >> 1, wc = w & 1;
    int rsub = lane >> 3, sl = lane & 7;
    int ssrc = sl ^ rsub;
    int fr = lane & 15, fh = lane >> 4;

    size_t arow[2], brow[4];
#pragma unroll
    for (int i = 0; i < 2; ++i) {
        int c = 2 * w + i;
        arow[i] = (size_t)(m0 + 8 * c + rsub) * K + ssrc * 8;
    }
#pragma unroll
    for (int i = 0; i < 4; ++i) {
        int c = 4 * w + i;
        brow[i] = (size_t)(n0 + 8 * c + rsub) * K + ssrc * 8;
    }

    f32x4 acc[2][4];
#pragma unroll
    for (int m = 0; m < 2; ++m)
#pragma unroll
        for (int n = 0; n < 4; ++n) acc[m][n] = 0.0f;

    int NT = K >> 6;
    for (int kt = 0; kt < NT; ++kt) {
        int kb = kt * 64;
#pragma unroll
        for (int i = 0; i < 2; ++i)
            __builtin_amdgcn_global_load_lds((gas_t)(const void*)(A + arow[i] + kb),
                                             (las_t)(void*)(&As[(2 * w + i) * 512]), 16, 0, 0);
#pragma unroll
        for (int i = 0; i < 4; ++i)
            __builtin_amdgcn_global_load_lds((gas_t)(const void*)(Bw + brow[i] + kb),
                                             (las_t)(void*)(&Bs[(4 * w + i) * 512]), 16, 0, 0);
        __syncthreads();
#pragma unroll
        for (int kk = 0; kk < 2; ++kk) {
            int slot = kk * 4 + fh;
            bf16x8 af[2], bfv[4];
#pragma unroll
            for (int m = 0; m < 2; ++m) {
                int row = wr * 32 + m * 16 + fr;
                af[m] = *reinterpret_cast<const bf16x8*>(&As[row * 64 + ((slot ^ (row & 7)) << 3)]);
            }
#pragma unroll
            for (int n = 0; n < 4; ++n) {
                int row = wc * 64 + n * 16 + fr;
                bfv[n] = *reinterpret_cast<const bf16x8*>(&Bs[row * 64 + ((slot ^ (row & 7)) << 3)]);
            }
#pragma unroll
            for (int m = 0; m < 2; ++m)
#pragma unroll
                for (int n = 0; n < 4; ++n)
                    acc[m][n] = __builtin_amdgcn_mfma_f32_16x16x32_bf16(af[m], bfv[n], acc[m][n], 0, 0, 0);
        }
        __syncthreads();
    }

    int rb = m0 + wr * 32 + fh * 4;
    int cb = n0 + wc * 64 + fr;
    int mat = n0 >> 10;

    if (mat < 2) {
        // fused per-head rms_norm + rope for q (mat 0) / k (mat 1)
        unsigned short* outp = (mat == 0) ? Qb : Kb;
#pragma unroll
        for (int m = 0; m < 2; ++m) {
#pragma unroll
            for (int j = 0; j < 4; ++j) {
                int gr = rb + m * 16 + j;
                int s = gr & (SS - 1);
                float ss = 0.0f;
#pragma unroll
                for (int n = 0; n < 4; ++n) ss += acc[m][n][j] * acc[m][n][j];
                ss += __shfl_xor(ss, 1, 64);
                ss += __shfl_xor(ss, 2, 64);
                ss += __shfl_xor(ss, 4, 64);
                ss += __shfl_xor(ss, 8, 64);
                float rsn = rsqrtf(ss * (1.0f / (float)HD) + 1e-6f);
                float nv0 = acc[m][0][j] * rsn;
                float nv1 = acc[m][1][j] * rsn;
                float nv2 = acc[m][2][j] * rsn;
                float nv3 = acc[m][3][j] * rsn;
                float2 t0 = tab[s * 32 + fr];
                float2 t1 = tab[s * 32 + fr + 16];
                float o0 = nv0 * t0.x + nv2 * t0.y;
                float o1 = nv1 * t1.x + nv3 * t1.y;
                float o2 = nv2 * t0.x - nv0 * t0.y;
                float o3 = nv3 * t1.x - nv1 * t1.y;
                size_t rowo = (size_t)gr * DM + (cb & 1023);
                outp[rowo] = f2bfb(o0);
                outp[rowo + 16] = f2bfb(o1);
                outp[rowo + 32] = f2bfb(o2);
                outp[rowo + 48] = f2bfb(o3);
            }
        }
    } else {
        // v path: copy (layer 0) or mix with v1
        float la = V1out ? 0.0f : *lambp;
#pragma unroll
        for (int n = 0; n < 4; ++n) {
            int gc = cb + n * 16;
#pragma unroll
            for (int m = 0; m < 2; ++m) {
#pragma unroll
                for (int j = 0; j < 4; ++j) {
                    int gr = rb + m * 16 + j;
                    size_t o = (size_t)gr * DM + (gc & 1023);
                    unsigned short bv = f2bfb(acc[m][n][j]);
                    if (V1out) {
                        Vb[o] = bv;
                        V1out[o] = bv;
                    } else {
                        float mixed = (1.0f - la) * bfb2f(bv) + la * bfb2f(V1in[o]);
                        Vb[o] = f2bfb(mixed);
                    }
                }
            }
        }
    }
}

// ---------- lm_head GEMM (single-buffer), fused softcap+exp partial-sum ----------
// exp(softcap(z)-30) == exp(-60/(t+1)) with t = exp(z/15)   [exact identity]
__global__ __launch_bounds__(256) void gemm_lm(
    const unsigned short* __restrict__ A, const unsigned short* __restrict__ Bw,
    const int* __restrict__ target, float* __restrict__ part, float* __restrict__ zbf,
    int K)
{
    __shared__ unsigned short As[128 * 64];
    __shared__ unsigned short Bs[128 * 64];
    __shared__ float reds[2][2][64];

    // bijective xcd chunking: nwg = 4704 = 8 * 588
    int orig = blockIdx.x;
    int xcd = orig & 7, rank = orig >> 3;
    int e = xcd * 588 + rank;
    int g = 0;
#pragma unroll
    for (int it = 0; it < 7; ++it) {
        int sz = (g & 1) ? 584 : 592;
        if (e >= sz) { e -= sz; ++g; }
    }
    int nj = g & 1, mi = g >> 1;
    int bxl = e >> 3, byl = e & 7;
    int bx = nj * 74 + bxl;
    int by = mi * 8 + byl;
    int m0 = by * 128, n0 = bx * 128;

    int tid = threadIdx.x, lane = tid & 63, w = tid >> 6;
    int wr = w >> 1, wc = w & 1;
    int rsub = lane >> 3, sl = lane & 7;
    int ssrc = sl ^ rsub;
    int fr = lane & 15, fh = lane >> 4;

    size_t arow[4], brow[4];
#pragma unroll
    for (int i = 0; i < 4; ++i) {
        int c = 4 * w + i;
        arow[i] = (size_t)(m0 + 8 * c + rsub) * K + ssrc * 8;
        brow[i] = (size_t)(n0 + 8 * c + rsub) * K + ssrc * 8;
    }

    f32x4 acc[4][4];
#pragma unroll
    for (int m = 0; m < 4; ++m)
#pragma unroll
        for (int n = 0; n < 4; ++n) acc[m][n] = 0.0f;

    int NT = K >> 6;
    for (int kt = 0; kt < NT; ++kt) {
        int kb = kt * 64;
#pragma unroll
        for (int i = 0; i < 4; ++i) {
            __builtin_amdgcn_global_load_lds((gas_t)(const void*)(A + arow[i] + kb),
                                             (las_t)(void*)(&As[(4 * w + i) * 512]), 16, 0, 0);
            __builtin_amdgcn_global_load_lds((gas_t)(const void*)(Bw + brow[i] + kb),
                                             (las_t)(void*)(&Bs[(4 * w + i) * 512]), 16, 0, 0);
        }
        __syncthreads();
#pragma unroll
        for (int kk = 0; kk < 2; ++kk) {
            int slot = kk * 4 + fh;
            bf16x8 af[4], bfv[4];
#pragma unroll
            for (int m = 0; m < 4; ++m) {
                int row = wr * 64 + m * 16 + fr;
                af[m] = *reinterpret_cast<const bf16x8*>(&As[row * 64 + ((slot ^ (row & 7)) << 3)]);
            }
#pragma unroll
            for (int n = 0; n < 4; ++n) {
                int row = wc * 64 + n * 16 + fr;
                bfv[n] = *reinterpret_cast<const bf16x8*>(&Bs[row * 64 + ((slot ^ (row & 7)) << 3)]);
            }
#pragma unroll
            for (int m = 0; m < 4; ++m)
#pragma unroll
                for (int n = 0; n < 4; ++n)
                    acc[m][n] = __builtin_amdgcn_mfma_f32_16x16x32_bf16(af[m], bfv[n], acc[m][n], 0, 0, 0);
        }
        __syncthreads();
    }

    int rb = m0 + wr * 64 + fh * 4;
    int cb = n0 + wc * 64 + fr;
#pragma unroll
    for (int m = 0; m < 4; ++m) {
#pragma unroll
        for (int j = 0; j < 4; ++j) {
            int gr = rb + m * 16 + j;
            int tg = target[gr];
            float rs = 0.0f;
#pragma unroll
            for (int n = 0; n < 4; ++n) {
                int gc = cb + n * 16;
                if (gc < VV) {
                    float zv = acc[m][n][j];
                    float tt = __expf(zv * 0.066666667f);     // exp(z/15)
                    rs += __expf(__fdividef(-60.0f, tt + 1.0f));
                    if (gc == tg) zbf[gr] = 30.0f - 60.0f / (tt + 1.0f);
                }
            }
            rs += __shfl_xor(rs, 1, 64);
            rs += __shfl_xor(rs, 2, 64);
            rs += __shfl_xor(rs, 4, 64);
            rs += __shfl_xor(rs, 8, 64);
            if (fr == 0) reds[wr][wc][m * 16 + fh * 4 + j] = rs;
        }
    }
    __syncthreads();
    if (tid < 128) {
        int wrx = tid >> 6, r64 = tid & 63;
        part[(size_t)(m0 + tid) * NXLM + bx] = reds[wrx][0][r64] + reds[wrx][1][r64];
    }
}

// merge NXLM partial sums per token -> loss = 30 + log(sum) - z_target
__global__ __launch_bounds__(256) void loss_merge_kernel(
    const float* __restrict__ part, const float* __restrict__ zbf,
    const int* __restrict__ target, float* __restrict__ out)
{
    int t = blockIdx.x;
    float l = 0.0f;
    for (int i = threadIdx.x; i < NXLM; i += 256) l += part[(size_t)t * NXLM + i];
    l = block_sum256(l);
    if (threadIdx.x == 0) {
        int tg = target[t];
        float lse = 30.0f + logf(l);
        bool masked = (tg == 16384) || (tg == 18433) || (tg == 18690);
        out[t] = masked ? 0.0f : (lse - zbf[t]);
    }
}

// ---------- BM=64 variant (wo, w1, w2); optional split-K with bf16 partial stores ----------
// EPI 0: bf16. EPI 1: relu^2 bf16. EPI 2: fp32 +=. EPI 4: bf16 partial store at ks*TT*DM.
template <int EPI, int KS = 1>
__global__ __launch_bounds__(256) void gemm_bb64(
    const unsigned short* __restrict__ A, const unsigned short* __restrict__ Bw,
    unsigned short* __restrict__ Cb, float* __restrict__ Cf,
    int NX, int K, int ldC)
{
    __shared__ unsigned short As[64 * 64];
    __shared__ unsigned short Bs[128 * 64];

    int nwg = gridDim.x;
    int orig = blockIdx.x;
    int qq = nwg >> 3, rr = nwg & 7;
    int xcd = orig & 7, rem = orig >> 3;
    int wg = (xcd < rr ? xcd * (qq + 1) : rr * (qq + 1) + (xcd - rr) * qq) + rem;
    int per = nwg / KS;
    int ks = (KS == 1) ? 0 : (wg / per);
    int rem2 = (KS == 1) ? wg : (wg % per);
    int bx = rem2 % NX, by = rem2 / NX;
    int m0 = by * 64, n0 = bx * 128;
    int KSUB = K / KS;
    int kbase = ks * KSUB;

    int tid = threadIdx.x, lane = tid & 63, w = tid >> 6;
    int wr = w >> 1, wc = w & 1;
    int rsub = lane >> 3, sl = lane & 7;
    int ssrc = sl ^ rsub;
    int fr = lane & 15, fh = lane >> 4;

    size_t arow[2], brow[4];
#pragma unroll
    for (int i = 0; i < 2; ++i) {
        int c = 2 * w + i;
        arow[i] = (size_t)(m0 + 8 * c + rsub) * K + ssrc * 8;
    }
#pragma unroll
    for (int i = 0; i < 4; ++i) {
        int c = 4 * w + i;
        brow[i] = (size_t)(n0 + 8 * c + rsub) * K + ssrc * 8;
    }

    f32x4 acc[2][4];
#pragma unroll
    for (int m = 0; m < 2; ++m)
#pragma unroll
        for (int n = 0; n < 4; ++n) acc[m][n] = 0.0f;

    int NT = KSUB >> 6;
    for (int kt = 0; kt < NT; ++kt) {
        int kb = kbase + kt * 64;
#pragma unroll
        for (int i = 0; i < 2; ++i)
            __builtin_amdgcn_global_load_lds((gas_t)(const void*)(A + arow[i] + kb),
                                             (las_t)(void*)(&As[(2 * w + i) * 512]), 16, 0, 0);
#pragma unroll
        for (int i = 0; i < 4; ++i)
            __builtin_amdgcn_global_load_lds((gas_t)(const void*)(Bw + brow[i] + kb),
                                             (las_t)(void*)(&Bs[(4 * w + i) * 512]), 16, 0, 0);
        __syncthreads();
#pragma unroll
        for (int kk = 0; kk < 2; ++kk) {
            int slot = kk * 4 + fh;
            bf16x8 af[2], bfv[4];
#pragma unroll
            for (int m = 0; m < 2; ++m) {
                int row = wr * 32 + m * 16 + fr;
                af[m] = *reinterpret_cast<const bf16x8*>(&As[row * 64 + ((slot ^ (row & 7)) << 3)]);
            }
#pragma unroll
            for (int n = 0; n < 4; ++n) {
                int row = wc * 64 + n * 16 + fr;
                bfv[n] = *reinterpret_cast<const bf16x8*>(&Bs[row * 64 + ((slot ^ (row & 7)) << 3)]);
            }
#pragma unroll
            for (int m = 0; m < 2; ++m)
#pragma unroll
                for (int n = 0; n < 4; ++n)
                    acc[m][n] = __builtin_amdgcn_mfma_f32_16x16x32_bf16(af[m], bfv[n], acc[m][n], 0, 0, 0);
        }
        __syncthreads();
    }

    int rb = m0 + wr * 32 + fh * 4;
    int cb = n0 + wc * 64 + fr;
#pragma unroll
    for (int n = 0; n < 4; ++n) {
        int gc = cb + n * 16;
#pragma unroll
        for (int m = 0; m < 2; ++m) {
#pragma unroll
            for (int j = 0; j < 4; ++j) {
                int gr = rb + m * 16 + j;
                float val = acc[m][n][j];
                if constexpr (EPI == 0) {
                    Cb[(size_t)gr * ldC + gc] = f2bfb(val);
                } else if constexpr (EPI == 1) {
                    float rl = fmaxf(val, 0.0f);
                    Cb[(size_t)gr * ldC + gc] = f2bfb(rl * rl);
                } else if constexpr (EPI == 2) {
                    size_t o = (size_t)gr * ldC + gc;
                    Cf[o] = Cf[o] + val;
                } else {
                    Cb[(size_t)ks * ((size_t)TT * DM) + (size_t)gr * ldC + gc] = f2bfb(val);
                }
            }
        }
    }
}

// MFMA flash attention, mask-sparse: local sliding-window pass + packed level>0 pass.
__global__ __launch_bounds__(256) void attn_mfma_kernel(
    const unsigned short* __restrict__ q, const unsigned short* __restrict__ k,
    const unsigned short* __restrict__ v,
    const unsigned short* __restrict__ kp, const unsigned short* __restrict__ vp,
    const int* __restrict__ gpos, const int* __restrict__ nbuf,
    unsigned short* __restrict__ y)
{
    __shared__ unsigned short Qs[64][APITCH];
    __shared__ unsigned short Ks[64][APITCH];
    __shared__ unsigned short Vt[64][APITCH];
    __shared__ unsigned short Ps[64][APITCH];
    __shared__ int posS[64];

    int bh = blockIdx.x;
    int b = bh >> 4, h = bh & 15;
    int q0 = blockIdx.y * 64;
    size_t base = (size_t)b * SS * DM + h * HD;
    int tid = threadIdx.x;
    int lane = tid & 63, w = tid >> 6;
    int srow = tid >> 2, sc = tid & 3;

    {
        const unsigned short* src = q + base + (size_t)(q0 + srow) * DM;
        *reinterpret_cast<uint4*>(&Qs[srow][sc * 8]) = *reinterpret_cast<const uint4*>(src + sc * 8);
        *reinterpret_cast<uint4*>(&Qs[srow][(sc + 4) * 8]) = *reinterpret_cast<const uint4*>(src + (sc + 4) * 8);
    }
    __syncthreads();

    int fr = lane & 15, fc = (lane >> 4) * 8;
    int rj = (lane >> 4) * 4;

    bf16x8 qa[2];
    qa[0] = *reinterpret_cast<const bf16x8*>(&Qs[w * 16 + fr][fc]);
    qa[1] = *reinterpret_cast<const bf16x8*>(&Qs[w * 16 + fr][32 + fc]);

    float mreg[4], lreg[4];
    f32x4 yacc[4];
#pragma unroll
    for (int j = 0; j < 4; ++j) { mreg[j] = -1e30f; lreg[j] = 0.0f; yacc[j] = 0.0f; }

    int nbp = nbuf[BBATCH + b];

    int t0 = (q0 >= 256) ? ((q0 - 256) >> 6) : 0;
    int t1 = q0 >> 6;
    for (int pass = 0; pass < 2; ++pass) {
        int kt_begin = (pass == 0) ? t0 : 0;
        int kt_end = (pass == 0) ? (t1 + 1) : (nbp >> 6);
        for (int kt = kt_begin; kt < kt_end; ++kt) {
            int k0 = kt * 64;
            if (pass == 1) {
                if (gpos[b * SS + k0] > q0 - 194) break;
            }
            __syncthreads();
            {
                const unsigned short* ksrc = (pass == 0) ? (k + base) : (kp + base);
                const unsigned short* vsrc = (pass == 0) ? (v + base) : (vp + base);
                size_t goff = (size_t)(k0 + srow) * DM;
                uint4 kv0 = *reinterpret_cast<const uint4*>(ksrc + goff + sc * 8);
                uint4 kv1 = *reinterpret_cast<const uint4*>(ksrc + goff + (sc + 4) * 8);
                *reinterpret_cast<uint4*>(&Ks[srow][sc * 8]) = kv0;
                *reinterpret_cast<uint4*>(&Ks[srow][(sc + 4) * 8]) = kv1;
                uint4 vv0 = *reinterpret_cast<const uint4*>(vsrc + goff + sc * 8);
                uint4 vv1 = *reinterpret_cast<const uint4*>(vsrc + goff + (sc + 4) * 8);
                const unsigned short* e0 = reinterpret_cast<const unsigned short*>(&vv0);
                const unsigned short* e1 = reinterpret_cast<const unsigned short*>(&vv1);
#pragma unroll
                for (int i = 0; i < 8; ++i) Vt[sc * 8 + i][srow] = e0[i];
#pragma unroll
                for (int i = 0; i < 8; ++i) Vt[(sc + 4) * 8 + i][srow] = e1[i];
                if (pass == 1 && tid < 64) posS[tid] = gpos[b * SS + k0 + tid];
            }
            __syncthreads();

            f32x4 sacc[4];
#pragma unroll
            for (int n = 0; n < 4; ++n) {
                bf16x8 kb0 = *reinterpret_cast<const bf16x8*>(&Ks[n * 16 + fr][fc]);
                bf16x8 kb1 = *reinterpret_cast<const bf16x8*>(&Ks[n * 16 + fr][32 + fc]);
                f32x4 a = {0.0f, 0.0f, 0.0f, 0.0f};
                a = __builtin_amdgcn_mfma_f32_16x16x32_bf16(qa[0], kb0, a, 0, 0, 0);
                a = __builtin_amdgcn_mfma_f32_16x16x32_bf16(qa[1], kb1, a, 0, 0, 0);
                sacc[n] = a;
            }

            float sm[4][4];
            float cm[4] = {-1e30f, -1e30f, -1e30f, -1e30f};
#pragma unroll
            for (int n = 0; n < 4; ++n) {
                int kg = (pass == 0) ? (k0 + n * 16 + fr) : posS[n * 16 + fr];
#pragma unroll
                for (int j = 0; j < 4; ++j) {
                    int qg = q0 + w * 16 + rj + j;
                    bool valid = (pass == 0) ? ((kg <= qg) && (qg - kg <= 256))
                                             : (kg < qg - 256);
                    float s = valid ? sacc[n][j] * 0.125f : -1e30f;
                    sm[n][j] = s;
                    cm[j] = fmaxf(cm[j], s);
                }
            }
#pragma unroll
            for (int j = 0; j < 4; ++j) {
                cm[j] = fmaxf(cm[j], __shfl_xor(cm[j], 1, 64));
                cm[j] = fmaxf(cm[j], __shfl_xor(cm[j], 2, 64));
                cm[j] = fmaxf(cm[j], __shfl_xor(cm[j], 4, 64));
                cm[j] = fmaxf(cm[j], __shfl_xor(cm[j], 8, 64));
            }
            float sj[4], ps[4];
#pragma unroll
            for (int j = 0; j < 4; ++j) {
                float nm = fmaxf(mreg[j], cm[j]);
                sj[j] = __expf(mreg[j] - nm);
                mreg[j] = nm;
                ps[j] = 0.0f;
            }
#pragma unroll
            for (int n = 0; n < 4; ++n) {
#pragma unroll
                for (int j = 0; j < 4; ++j) {
                    float p = (sm[n][j] > -1e29f) ? __expf(sm[n][j] - mreg[j]) : 0.0f;
                    Ps[w * 16 + rj + j][n * 16 + fr] = f2bfb(p);
                    ps[j] += p;
                }
            }
#pragma unroll
            for (int j = 0; j < 4; ++j) {
                float t = ps[j];
                t += __shfl_xor(t, 1, 64); t += __shfl_xor(t, 2, 64);
                t += __shfl_xor(t, 4, 64); t += __shfl_xor(t, 8, 64);
                lreg[j] = lreg[j] * sj[j] + t;
            }
#pragma unroll
            for (int n = 0; n < 4; ++n)
#pragma unroll
                for (int j = 0; j < 4; ++j) yacc[n][j] *= sj[j];

            bf16x8 pa0 = *reinterpret_cast<const bf16x8*>(&Ps[w * 16 + fr][fc]);
            bf16x8 pa1 = *reinterpret_cast<const bf16x8*>(&Ps[w * 16 + fr][32 + fc]);
#pragma unroll
            for (int n = 0; n < 4; ++n) {
                bf16x8 vb0 = *reinterpret_cast<const bf16x8*>(&Vt[n * 16 + fr][fc]);
                bf16x8 vb1 = *reinterpret_cast<const bf16x8*>(&Vt[n * 16 + fr][32 + fc]);
                yacc[n] = __builtin_amdgcn_mfma_f32_16x16x32_bf16(pa0, vb0, yacc[n], 0, 0, 0);
                yacc[n] = __builtin_amdgcn_mfma_f32_16x16x32_bf16(pa1, vb1, yacc[n], 0, 0, 0);
            }
        }
    }

    float inv[4];
#pragma unroll
    for (int j = 0; j < 4; ++j) inv[j] = 1.0f / lreg[j];
#pragma unroll
    for (int n = 0; n < 4; ++n) {
#pragma unroll
        for (int j = 0; j < 4; ++j) {
            int qg = q0 + w * 16 + rj + j;
            y[base + (size_t)qg * DM + n * 16 + fr] = f2bfb(yacc[n][j] * inv[j]);
        }
    }
}

extern "C" void kernel_launch(void* const* d_in, const int* in_sizes, int n_in,
                              void* d_out, int out_size, void* d_ws, size_t ws_size,
                              hipStream_t stream)
{
    const int* idx = (const int*)d_in[0];
    const int* target = (const int*)d_in[1];
    const float* wte = (const float*)d_in[2];
    const float* lambdas = (const float*)d_in[3];
    const float* lamb = (const float*)d_in[4];
    const float* wq = (const float*)d_in[5];
    const float* wk = (const float*)d_in[6];
    const float* wv = (const float*)d_in[7];
    const float* wo = (const float*)d_in[8];
    const float* w1 = (const float*)d_in[9];
    const float* w2 = (const float*)d_in[10];
    const float* lm_head = (const float*)d_in[11];
    float* out = (float*)d_out;

    char* ws = (char*)d_ws;
    const size_t MB = (size_t)1 << 20;
    float* x            = (float*)(ws);
    unsigned short* x0  = (unsigned short*)(ws + 16 * MB);
    unsigned short* nrm = (unsigned short*)(ws + 24 * MB);
    unsigned short* qb  = (unsigned short*)(ws + 32 * MB);
    unsigned short* kb  = (unsigned short*)(ws + 40 * MB);
    unsigned short* vb  = (unsigned short*)(ws + 48 * MB);
    unsigned short* v1b = (unsigned short*)(ws + 56 * MB);
    unsigned short* yb  = (unsigned short*)(ws + 64 * MB);
    unsigned short* hid = (unsigned short*)(ws + 72 * MB);   // 32 MB; dead during attention & lm
    unsigned short* kp  = (unsigned short*)(ws + 72 * MB);   // packed K (8 MB), overlaps hid
    unsigned short* vp  = (unsigned short*)(ws + 80 * MB);   // packed V (8 MB), overlaps hid
    float* part         = (float*)(ws + 72 * MB);            // lm partials (2.4 MB), lm-time only
    float* zbf          = (float*)(ws + 78 * MB);            // lm target logit (16 KB), lm-time only
    unsigned short* w2p = qb;                                 // w2 split-K partials (qb+kb, dead then)
    int* levels         = (int*)(ws + 104 * MB);
    int* gpos           = (int*)(ws + 104 * MB + 64 * 1024);
    int* nbuf           = (int*)(ws + 104 * MB + 128 * 1024);
    float2* ropetab     = (float2*)(ws + 104 * MB + 256 * 1024); // 512 KB, persistent
    unsigned short* wqkvb = (unsigned short*)(ws + 105 * MB); // [NL][3][1024][1024]
    unsigned short* wob = (unsigned short*)(ws + 129 * MB);
    unsigned short* w1b = (unsigned short*)(ws + 137 * MB);
    unsigned short* w2b = (unsigned short*)(ws + 169 * MB);
    unsigned short* lmb = (unsigned short*)(ws + 201 * MB);
    bool cvt = ws_size >= 238 * MB;

    if (cvt) {
        int n1 = DM * DM;
        int nff = NL * FFD * DM;
        for (int i = 0; i < NL; ++i) {
            cvtw_kernel<<<n1 / 1024, 256, 0, stream>>>(wq + (size_t)i * n1, wqkvb + ((size_t)i * 3 + 0) * n1, n1);
            cvtw_kernel<<<n1 / 1024, 256, 0, stream>>>(wk + (size_t)i * n1, wqkvb + ((size_t)i * 3 + 1) * n1, n1);
            cvtw_kernel<<<n1 / 1024, 256, 0, stream>>>(wv + (size_t)i * n1, wqkvb + ((size_t)i * 3 + 2) * n1, n1);
        }
        cvtw_kernel<<<NL * n1 / 1024, 256, 0, stream>>>(wo, wob, NL * n1);
        cvtw_kernel<<<nff / 1024, 256, 0, stream>>>(w1, w1b, nff);
        cvtw_kernel<<<nff / 1024, 256, 0, stream>>>(w2, w2b, nff);
        cvtpad_kernel<<<(VP * DM) / 1024, 256, 0, stream>>>(lm_head, lmb, VV * DM, VP * DM);
    }
    ropetab_kernel<<<SS / 8, 256, 0, stream>>>(ropetab);

    embed_kernel<<<TT, 256, 0, stream>>>(idx, wte, x, x0, levels);
    pack_kernel<<<BBATCH, 256, 0, stream>>>(levels, gpos, nbuf);
    mixnorm_kernel<<<TT, 256, 0, stream>>>(x, x0, lambdas, nrm);

    for (int i = 0; i < NL; ++i) {
        if (cvt) {
            if (i == 0)
                gemm_qkv64<<<1536, 256, 0, stream>>>(nrm, wqkvb + (size_t)i * 3 * DM * DM,
                                                     qb, kb, vb, nullptr, v1b, nullptr, ropetab, DM);
            else
                gemm_qkv64<<<1536, 256, 0, stream>>>(nrm, wqkvb + (size_t)i * 3 * DM * DM,
                                                     qb, kb, vb, v1b, nullptr, lamb + i, ropetab, DM);
        }
        gather_kernel<<<BBATCH * SS / 4, 256, 0, stream>>>(kb, vb, gpos, nbuf, kp, vp);
        attn_mfma_kernel<<<dim3(BBATCH * NH, SS / 64), 256, 0, stream>>>(qb, kb, vb, kp, vp, gpos, nbuf, yb);
        if (cvt) {
            gemm_bb64<2><<<512, 256, 0, stream>>>(yb, wob + (size_t)i * DM * DM, nullptr, x, 8, DM, DM);
            norm_kernel<<<TT, 256, 0, stream>>>(x, nrm);
            gemm_bb64<1><<<2048, 256, 0, stream>>>(nrm, w1b + (size_t)i * FFD * DM, hid, nullptr, 32, DM, FFD);
            gemm_bb64<4, 2><<<1024, 256, 0, stream>>>(hid, w2b + (size_t)i * DM * FFD, w2p, nullptr, 8, FFD, DM);
            if (i < NL - 1)
                w2mix_kernel<<<TT, 256, 0, stream>>>(x, w2p, w2p + (size_t)TT * DM, x0,
                                                     lambdas + 2 * (i + 1), nrm, 1);
            else
                w2mix_kernel<<<TT, 256, 0, stream>>>(x, w2p, w2p + (size_t)TT * DM, x0,
                                                     nullptr, nrm, 0);
        }
    }

    gemm_lm<<<NXLM * 32, 256, 0, stream>>>(nrm, lmb, target, part, zbf, DM);
    loss_merge_kernel<<<TT, 256, 0, stream>>>(part, zbf, target, out);
}